// Round 8
// baseline (525.429 us; speedup 1.0000x reference)
//
#include <hip/hip_runtime.h>
#include <hip/hip_bf16.h>

// GCN: h1 = relu(Agg(x@W1)+b1); h2 = relu(Agg(h1@W2)+b2); out = mean(h2)@Wc + bc
// Agg via CSR gather; g = (X@W)*dinv stored OCP fp8 e4m3 (128B rows).
// CSR build is two-phase radix-binned by dst-partition (8 bins = 8 XCDs):
//   binhist -> binscan (exact offsets) -> binfill (pack (src,dst) per bin)
//   -> count_bin / scat_bin operate partition-locally (cnt/cursor/csr_src
//   slices stay L2-resident; no cross-XCD line bouncing, no 8x dst re-read).
// GEMMs: mfma_f32_16x16x32_bf16, LDS-free, W pre-packed to k-block layout.

#define FEAT 128
#define CHUNK 16384   // edges per bin chunk
#define NPB 64        // blocks per partition in count_bin/scat_bin

typedef __attribute__((ext_vector_type(8))) short short8;
typedef __attribute__((ext_vector_type(4))) float float4v;
typedef __attribute__((ext_vector_type(2))) float floatx2;

union I4S8 { int4 i; short8 s; };

static __device__ inline unsigned short f2bf(float f) {
    union { __hip_bfloat16 h; unsigned short u; } cv;
    cv.h = __float2bfloat16(f);
    return cv.u;
}

static __device__ inline int dpart(int d, float pscale) {
    return min(7, (int)(d * pscale));
}

// ---- OCP fp8 e4m3 helpers ----
static __device__ inline floatx2 fp8x2_dec(unsigned int u) {
#if __has_builtin(__builtin_amdgcn_cvt_pk_f32_fp8)
    return __builtin_amdgcn_cvt_pk_f32_fp8((int)u, false);
#else
    floatx2 r;
    unsigned int b0 = u & 0xFFu, b1 = (u >> 8) & 0xFFu;
    r.x = __uint_as_float(((b0 & 0x80u) << 24) | ((b0 & 0x7Fu) << 20)) * 0x1p+120f;
    r.y = __uint_as_float(((b1 & 0x80u) << 24) | ((b1 & 0x7Fu) << 20)) * 0x1p+120f;
    return r;
#endif
}

static __device__ inline unsigned char fp8enc(float f) {
#if __has_builtin(__builtin_amdgcn_cvt_pk_fp8_f32)
    return (unsigned char)(__builtin_amdgcn_cvt_pk_fp8_f32(f, 0.0f, 0, false) & 0xFF);
#else
    unsigned int u = __float_as_uint(f);
    unsigned int s = (u >> 24) & 0x80u;
    float a = fabsf(f);
    a = fminf(a, 448.0f);
    unsigned int code;
    if (a < 0.015625f) {
        code = (unsigned int)(int)rintf(a * 512.0f);
    } else {
        unsigned int au = __float_as_uint(a);
        unsigned int r = au + 0x0007FFFFu + ((au >> 20) & 1u);
        unsigned int e = (r >> 23) - 120u;
        unsigned int m = (r >> 20) & 7u;
        code = (e << 3) | m;
        if (code > 0x7Eu) code = 0x7Eu;
    }
    return (unsigned char)(code | s);
#endif
}

// ---- bin phase 1: per-chunk dst-partition histogram -> hist[p*NC+c] ----
__global__ __launch_bounds__(256) void binhist(const int* __restrict__ dst,
                                               int* __restrict__ hist,
                                               int nE, int NC, float pscale) {
    __shared__ int h[8];
    if (threadIdx.x < 8) h[threadIdx.x] = 0;
    __syncthreads();
    int c = blockIdx.x;
    int beg = c * CHUNK, end = min(nE, beg + CHUNK);
    for (int e = beg + (int)threadIdx.x; e < end; e += 256)
        atomicAdd(&h[dpart(dst[e], pscale)], 1);
    __syncthreads();
    if (threadIdx.x < 8) hist[threadIdx.x * NC + c] = h[threadIdx.x];
}

// ---- bin phase 2: exclusive scan of hist (partition-major, M = 8*NC <= 1024) ----
__global__ __launch_bounds__(256) void binscan(const int* __restrict__ hist,
                                               int* __restrict__ off, int M) {
    __shared__ int sc[256];
    int t = threadIdx.x;
    int base = t * 4;
    int v[4];
    int s = 0;
#pragma unroll
    for (int k = 0; k < 4; k++) {
        int i = base + k;
        v[k] = (i < M) ? hist[i] : 0;
        s += v[k];
    }
    sc[t] = s;
    __syncthreads();
    for (int o = 1; o < 256; o <<= 1) {
        int add = (t >= o) ? sc[t - o] : 0;
        __syncthreads();
        sc[t] += add;
        __syncthreads();
    }
    int excl = sc[t] - s;
#pragma unroll
    for (int k = 0; k < 4; k++) {
        int i = base + k;
        if (i < M) off[i] = excl;
        excl += v[k];
    }
}

// ---- bin phase 3: pack (src,dst) into partition bins ----
__global__ __launch_bounds__(256) void binfill(const int* __restrict__ src,
                                               const int* __restrict__ dst,
                                               const int* __restrict__ off,
                                               int2* __restrict__ binned,
                                               int nE, int NC, float pscale) {
    __shared__ int cur[8];
    int c = blockIdx.x;
    if (threadIdx.x < 8) cur[threadIdx.x] = off[threadIdx.x * NC + c];
    __syncthreads();
    int beg = c * CHUNK, end = min(nE, beg + CHUNK);
    for (int e = beg + (int)threadIdx.x; e < end; e += 256) {
        int d = dst[e];
        int pos = atomicAdd(&cur[dpart(d, pscale)], 1);
        binned[pos] = make_int2(src[e], d);
    }
}

// ---- degree count from binned (partition-local atomics) ----
__global__ __launch_bounds__(256) void count_bin(const int2* __restrict__ binned,
                                                 const int* __restrict__ off,
                                                 int* __restrict__ cnt,
                                                 int nE, int NC) {
    int p = blockIdx.x & 7, blk = blockIdx.x >> 3;
    int beg = off[p * NC];
    int end = (p == 7) ? nE : off[(p + 1) * NC];
    for (int i = beg + blk * 256 + (int)threadIdx.x; i < end; i += NPB * 256)
        atomicAdd(&cnt[binned[i].y], 1);
}

// ---- scan K1: per-block (1024 elems) sums ----
__global__ __launch_bounds__(256) void scan_bsum(const int* __restrict__ cnt,
                                                 int* __restrict__ bsum, int n) {
    __shared__ int red[256];
    int b = blockIdx.x, t = threadIdx.x;
    int base = b * 1024 + t * 4;
    int s = 0;
#pragma unroll
    for (int k = 0; k < 4; k++) {
        int i = base + k;
        if (i < n) s += cnt[i];
    }
    red[t] = s;
    __syncthreads();
    for (int off = 128; off > 0; off >>= 1) {
        if (t < off) red[t] += red[t + off];
        __syncthreads();
    }
    if (t == 0) bsum[b] = red[0];
}

// ---- scan K2: exclusive scan of block sums (single thread; nb ~ 98) ----
__global__ void scan_boff(const int* __restrict__ bsum, int* __restrict__ boff, int nb) {
    int run = 0;
    for (int i = 0; i < nb; i++) { boff[i] = run; run += bsum[i]; }
}

// ---- scan K3: cursor[i] = global exclusive prefix; also dinv = rsqrt(cnt+1) ----
__global__ __launch_bounds__(256) void scan_write(const int* __restrict__ cnt,
                                                  const int* __restrict__ boff,
                                                  int* __restrict__ cursor,
                                                  float* __restrict__ dinv, int n) {
    __shared__ int sc[256];
    int b = blockIdx.x, t = threadIdx.x;
    int base = b * 1024 + t * 4;
    int v[4];
    int s = 0;
#pragma unroll
    for (int k = 0; k < 4; k++) {
        int i = base + k;
        v[k] = (i < n) ? cnt[i] : 0;
        s += v[k];
    }
    sc[t] = s;
    __syncthreads();
    for (int off = 1; off < 256; off <<= 1) {
        int add = (t >= off) ? sc[t - off] : 0;
        __syncthreads();
        sc[t] += add;
        __syncthreads();
    }
    int excl = boff[b] + sc[t] - s;
#pragma unroll
    for (int k = 0; k < 4; k++) {
        int i = base + k;
        if (i < n) {
            cursor[i] = excl;
            dinv[i] = rsqrtf((float)(v[k] + 1));
        }
        excl += v[k];
    }
}

// ---- scatter from binned into CSR buckets (partition-local) ----
__global__ __launch_bounds__(256) void scat_bin(const int2* __restrict__ binned,
                                                const int* __restrict__ off,
                                                int* __restrict__ cursor,
                                                int* __restrict__ csr_src,
                                                int nE, int NC) {
    int p = blockIdx.x & 7, blk = blockIdx.x >> 3;
    int beg = off[p * NC];
    int end = (p == 7) ? nE : off[(p + 1) * NC];
    for (int i = beg + blk * 256 + (int)threadIdx.x; i < end; i += NPB * 256) {
        int2 e = binned[i];
        int pos = atomicAdd(&cursor[e.y], 1);
        csr_src[pos] = e.x;
    }
}

// ---- W pre-pack: Wbf[(kb*128+n)*8+j] = bf16(W[(kb*8+j)*128+n]) ----
__global__ __launch_bounds__(256) void wprep(const float* __restrict__ W,
                                             unsigned short* __restrict__ Wbf) {
    int tid = blockIdx.x * 256 + threadIdx.x;   // 16384 threads
    int chunk = tid >> 3, j = tid & 7;
    int kb = chunk >> 7, nn = chunk & 127;
    Wbf[tid] = f2bf(W[(kb * 8 + j) * FEAT + nn]);
}

// ---- MFMA GEMM: gout[N][128](fp8) = bf16(X) @ Wbf * dinv[row] ----
template <bool AFP32>
__global__ __launch_bounds__(256) void gemm_mfma(const void* __restrict__ Xv,
                                                 const unsigned short* __restrict__ Wbf,
                                                 const float* __restrict__ dinv,
                                                 unsigned char* __restrict__ gout,
                                                 int n) {
    int wave = threadIdx.x >> 6, lane = threadIdx.x & 63;
    int m0 = blockIdx.x * 64 + wave * 16;
    if (m0 >= n) return;
    int col = lane & 15, quad = lane >> 4;
    int mc = min(m0 + col, n - 1);

    short8 afr[4];
    if (AFP32) {
        const float* X = (const float*)Xv;
        const float* xr = X + (size_t)mc * FEAT + quad * 8;
#pragma unroll
        for (int ks = 0; ks < 4; ks++) {
            float4 lo = *(const float4*)(xr + ks * 32);
            float4 hi = *(const float4*)(xr + ks * 32 + 4);
            short8 a;
            a[0] = (short)f2bf(lo.x); a[1] = (short)f2bf(lo.y);
            a[2] = (short)f2bf(lo.z); a[3] = (short)f2bf(lo.w);
            a[4] = (short)f2bf(hi.x); a[5] = (short)f2bf(hi.y);
            a[6] = (short)f2bf(hi.z); a[7] = (short)f2bf(hi.w);
            afr[ks] = a;
        }
    } else {
        const int4* X = (const int4*)Xv;
        const int4* xr = X + (size_t)mc * (FEAT / 8) + quad;
#pragma unroll
        for (int ks = 0; ks < 4; ks++) {
            I4S8 u; u.i = xr[ks * 4];
            afr[ks] = u.s;
        }
    }

    float dvr[4];
#pragma unroll
    for (int r = 0; r < 4; r++)
        dvr[r] = dinv[min(m0 + quad * 4 + r, n - 1)];

    const int4* Wb = (const int4*)Wbf;
#pragma unroll
    for (int nt = 0; nt < 8; nt++) {
        float4v acc = {0.f, 0.f, 0.f, 0.f};
#pragma unroll
        for (int ks = 0; ks < 4; ks++) {
            int kb = ks * 4 + quad;
            I4S8 u; u.i = Wb[kb * FEAT + nt * 16 + col];
            acc = __builtin_amdgcn_mfma_f32_16x16x32_bf16(afr[ks], u.s, acc, 0, 0, 0);
        }
#pragma unroll
        for (int r = 0; r < 4; r++) {
            int row = m0 + quad * 4 + r;
            if (row < n)
                gout[(size_t)row * FEAT + nt * 16 + col] = fp8enc(acc[r] * dvr[r]);
        }
    }
}

// ---- fused CSR aggregate + bias + relu. One wave/node, 2 fp8 feats/lane ----
__global__ __launch_bounds__(256) void agg_csr(const int* __restrict__ cursor,
                                               const int* __restrict__ cnt,
                                               const int* __restrict__ csr_src,
                                               const unsigned short* __restrict__ gs,
                                               const float* __restrict__ dinv,
                                               const float* __restrict__ bias,
                                               __hip_bfloat162* __restrict__ outb,
                                               int n) {
    int node = blockIdx.x * 4 + (threadIdx.x >> 6);
    if (node >= n) return;
    int lane = threadIdx.x & 63;

    int num = cnt[node];
    int end = cursor[node];       // after scatter, cursor = bucket end
    int beg = end - num;

    floatx2 sl = fp8x2_dec(gs[(size_t)node * 64 + lane]);   // self-loop term
    float ax[4] = {sl.x, 0.f, 0.f, 0.f};
    float ay[4] = {sl.y, 0.f, 0.f, 0.f};

    int j = beg;
    for (; j + 15 < end; j += 16) {
        int sIdx[16];
#pragma unroll
        for (int k = 0; k < 16; k++) sIdx[k] = csr_src[j + k];
        unsigned int uu[16];
#pragma unroll
        for (int k = 0; k < 16; k++) uu[k] = gs[(size_t)sIdx[k] * 64 + lane];
#pragma unroll
        for (int k = 0; k < 16; k++) {
            floatx2 v = fp8x2_dec(uu[k]);
            ax[k & 3] += v.x;
            ay[k & 3] += v.y;
        }
    }
    for (; j + 3 < end; j += 4) {
        int sIdx[4];
#pragma unroll
        for (int k = 0; k < 4; k++) sIdx[k] = csr_src[j + k];
        unsigned int uu[4];
#pragma unroll
        for (int k = 0; k < 4; k++) uu[k] = gs[(size_t)sIdx[k] * 64 + lane];
#pragma unroll
        for (int k = 0; k < 4; k++) {
            floatx2 v = fp8x2_dec(uu[k]);
            ax[k] += v.x;
            ay[k] += v.y;
        }
    }
    for (; j < end; j++) {
        floatx2 v = fp8x2_dec(gs[(size_t)csr_src[j] * 64 + lane]);
        ax[0] += v.x;
        ay[0] += v.y;
    }

    float dv = dinv[node];
    float2 bv = ((const float2*)bias)[lane];
    float sx = (ax[0] + ax[1]) + (ax[2] + ax[3]);
    float sy = (ay[0] + ay[1]) + (ay[2] + ay[3]);
    float2 r;
    r.x = fmaxf(sx * dv + bv.x, 0.0f);
    r.y = fmaxf(sy * dv + bv.y, 0.0f);
    outb[(size_t)node * 64 + lane] = __float22bfloat162_rn(r);
}

// ---- mean pool stage 1 (bf16 input) ----
__global__ __launch_bounds__(256) void pool_kernel(const __hip_bfloat16* __restrict__ a,
                                                   float* __restrict__ pooled, int n) {
    int tid = blockIdx.x * 256 + threadIdx.x;  // 256 blocks -> 65536 threads
    int f = tid & 127;
    int i0 = tid >> 7;  // 0..511
    float s = 0.0f;
    for (int i = i0; i < n; i += 512) s += __bfloat162float(a[(size_t)i * FEAT + f]);
    atomicAdd(&pooled[f], s);
}

// ---- final: out[c] = (pooled/N) . Wc[:,c] + bc[c] ----
__global__ __launch_bounds__(128) void final_kernel(const float* __restrict__ pooled,
                                                    const float* __restrict__ Wc,
                                                    const float* __restrict__ bc,
                                                    float* __restrict__ out,
                                                    int n, int C) {
    __shared__ float p[FEAT];
    int t = threadIdx.x;
    p[t] = pooled[t] * (1.0f / (float)n);
    __syncthreads();
    if (t < C) {
        float acc = bc[t];
        for (int h = 0; h < FEAT; h++)
            acc += p[h] * Wc[h * C + t];
        out[t] = acc;
    }
}

extern "C" void kernel_launch(void* const* d_in, const int* in_sizes, int n_in,
                              void* d_out, int out_size, void* d_ws, size_t ws_size,
                              hipStream_t stream) {
    const float* x  = (const float*)d_in[0];
    const int*   ei = (const int*)d_in[1];
    const float* W1 = (const float*)d_in[2];
    const float* b1 = (const float*)d_in[3];
    const float* W2 = (const float*)d_in[4];
    const float* b2 = (const float*)d_in[5];
    const float* Wc = (const float*)d_in[6];
    const float* bc = (const float*)d_in[7];

    const int N = in_sizes[0] / FEAT;      // 100000
    const int E = in_sizes[1] / 2;         // 1600000
    const int C = out_size;                // 32
    const int* srcI = ei;
    const int* dstI = ei + E;
    const int NB = (N + 1023) / 1024;      // node-scan blocks
    const int NC = (E + CHUNK - 1) / CHUNK;  // edge chunks (98)
    const float pscale = 8.0f / (float)N;

    // workspace carve (256B aligned)
    auto align256 = [](size_t v) { return (v + 255) & ~(size_t)255; };
    char* w = (char*)d_ws;
    int*            cnt     = (int*)w;            w += align256((size_t)N * 4);
    float*          dinv    = (float*)w;          w += align256((size_t)N * 4);
    int*            cursor  = (int*)w;            w += align256((size_t)N * 4);
    int*            csr_src = (int*)w;            w += align256((size_t)E * 4);
    int2*           binned  = (int2*)w;           w += align256((size_t)E * 8);
    int*            hist    = (int*)w;            w += align256((size_t)8 * NC * 4);
    int*            hoff    = (int*)w;            w += align256((size_t)8 * NC * 4);
    int*            bsum    = (int*)w;            w += align256((size_t)NB * 4);
    int*            boff    = (int*)w;            w += align256((size_t)NB * 4);
    unsigned short* Wbf1    = (unsigned short*)w; w += align256((size_t)FEAT * FEAT * 2);
    unsigned short* Wbf2    = (unsigned short*)w; w += align256((size_t)FEAT * FEAT * 2);
    unsigned char*  gbuf    = (unsigned char*)w;  w += align256((size_t)N * FEAT);
    unsigned short* bufA    = (unsigned short*)w; w += align256((size_t)N * FEAT * 2);
    float*          pooled  = (float*)w;          w += align256((size_t)FEAT * 4);

    hipMemsetAsync(cnt, 0, (size_t)N * 4, stream);
    hipMemsetAsync(pooled, 0, (size_t)FEAT * 4, stream);

    // W pre-pack (tiny)
    wprep<<<64, 256, 0, stream>>>(W1, Wbf1);
    wprep<<<64, 256, 0, stream>>>(W2, Wbf2);

    // ---- binned CSR build ----
    binhist<<<NC, 256, 0, stream>>>(dstI, hist, E, NC, pscale);
    binscan<<<1, 256, 0, stream>>>(hist, hoff, 8 * NC);
    binfill<<<NC, 256, 0, stream>>>(srcI, dstI, hoff, binned, E, NC, pscale);
    count_bin<<<NPB * 8, 256, 0, stream>>>(binned, hoff, cnt, E, NC);
    scan_bsum<<<NB, 256, 0, stream>>>(cnt, bsum, N);
    scan_boff<<<1, 1, 0, stream>>>(bsum, boff, NB);
    scan_write<<<NB, 256, 0, stream>>>(cnt, boff, cursor, dinv, N);
    scat_bin<<<NPB * 8, 256, 0, stream>>>(binned, hoff, cursor, csr_src, E, NC);

    const int gAgg = (N + 3) / 4;
    const int gGemm = (N + 63) / 64;

    // ---- layer 1 ----
    gemm_mfma<true><<<gGemm, 256, 0, stream>>>(x, Wbf1, dinv, gbuf, N);
    agg_csr<<<gAgg, 256, 0, stream>>>(cursor, cnt, csr_src,
                                      (const unsigned short*)gbuf, dinv, b1,
                                      (__hip_bfloat162*)bufA, N);

    // ---- layer 2 ----
    gemm_mfma<false><<<gGemm, 256, 0, stream>>>(bufA, Wbf2, dinv, gbuf, N);
    agg_csr<<<gAgg, 256, 0, stream>>>(cursor, cnt, csr_src,
                                      (const unsigned short*)gbuf, dinv, b2,
                                      (__hip_bfloat162*)bufA, N);

    // ---- pool + classifier ----
    pool_kernel<<<256, 256, 0, stream>>>((const __hip_bfloat16*)bufA, pooled, N);
    final_kernel<<<1, 128, 0, stream>>>(pooled, Wc, bc, (float*)d_out, N, C);
}

// Round 9
// 460.538 us; speedup vs baseline: 1.1409x; 1.1409x over previous
//
#include <hip/hip_runtime.h>
#include <hip/hip_bf16.h>

// GCN: h1 = relu(Agg(x@W1)+b1); h2 = relu(Agg(h1@W2)+b2); out = mean(h2)@Wc + bc
// Agg via CSR gather; g = (X@W)*dinv stored OCP fp8 e4m3 (128B rows).
// CSR build is ATOMIC-FREE (global atomics write through EA ~16-40B each —
// measured r2/r8): LDS histograms + exact prefix offsets + LDS cursors.
//   hist2 (per chunk, 391 node-buckets) -> 3 tiny scans -> fill2 (bucket-
//   grouped binned) -> bucket_scat (per bucket: LDS count/scan/scatter,
//   writes cnt/dinv/cursor/csr_src in private contiguous regions).
// GEMMs: mfma_f32_16x16x32_bf16, LDS-free, W pre-packed to k-block layout.

#define FEAT 128
#define CHUNK 16384     // edges per chunk
#define MAXBUCK 1024    // max node-buckets (N <= 262144)
#define ECAP 6144       // LDS edge staging cap in bucket_scat (48 KB)

typedef __attribute__((ext_vector_type(8))) short short8;
typedef __attribute__((ext_vector_type(4))) float float4v;
typedef __attribute__((ext_vector_type(2))) float floatx2;

union I4S8 { int4 i; short8 s; };

static __device__ inline unsigned short f2bf(float f) {
    union { __hip_bfloat16 h; unsigned short u; } cv;
    cv.h = __float2bfloat16(f);
    return cv.u;
}

// ---- OCP fp8 e4m3 helpers ----
static __device__ inline floatx2 fp8x2_dec(unsigned int u) {
#if __has_builtin(__builtin_amdgcn_cvt_pk_f32_fp8)
    return __builtin_amdgcn_cvt_pk_f32_fp8((int)u, false);
#else
    floatx2 r;
    unsigned int b0 = u & 0xFFu, b1 = (u >> 8) & 0xFFu;
    r.x = __uint_as_float(((b0 & 0x80u) << 24) | ((b0 & 0x7Fu) << 20)) * 0x1p+120f;
    r.y = __uint_as_float(((b1 & 0x80u) << 24) | ((b1 & 0x7Fu) << 20)) * 0x1p+120f;
    return r;
#endif
}

static __device__ inline unsigned char fp8enc(float f) {
#if __has_builtin(__builtin_amdgcn_cvt_pk_fp8_f32)
    return (unsigned char)(__builtin_amdgcn_cvt_pk_fp8_f32(f, 0.0f, 0, false) & 0xFF);
#else
    unsigned int u = __float_as_uint(f);
    unsigned int s = (u >> 24) & 0x80u;
    float a = fabsf(f);
    a = fminf(a, 448.0f);
    unsigned int code;
    if (a < 0.015625f) {
        code = (unsigned int)(int)rintf(a * 512.0f);
    } else {
        unsigned int au = __float_as_uint(a);
        unsigned int r = au + 0x0007FFFFu + ((au >> 20) & 1u);
        unsigned int e = (r >> 23) - 120u;
        unsigned int m = (r >> 20) & 7u;
        code = (e << 3) | m;
        if (code > 0x7Eu) code = 0x7Eu;
    }
    return (unsigned char)(code | s);
#endif
}

// ---- build phase 1: per-chunk histogram over node buckets (dst>>8) ----
__global__ __launch_bounds__(256) void hist2(const int* __restrict__ dst,
                                             int* __restrict__ hist,
                                             int nE, int NC, int nbuck) {
    __shared__ int h[MAXBUCK];
    int c = blockIdx.x, t = threadIdx.x;
    for (int i = t; i < nbuck; i += 256) h[i] = 0;
    __syncthreads();
    int beg = c * CHUNK, end = min(nE, beg + CHUNK);
    for (int e = beg + t; e < end; e += 256)
        atomicAdd(&h[dst[e] >> 8], 1);
    __syncthreads();
    for (int i = t; i < nbuck; i += 256) hist[i * NC + c] = h[i];
}

// ---- phase 2a: bucket totals ----
__global__ __launch_bounds__(512) void rowsum(const int* __restrict__ hist,
                                              int* __restrict__ tot, int NC, int nbuck) {
    for (int b = threadIdx.x; b < nbuck; b += 512) {
        int s = 0;
        for (int c = 0; c < NC; c++) s += hist[b * NC + c];
        tot[b] = s;
    }
}

// ---- phase 2b: exclusive scan of bucket totals -> bboff[0..nbuck] ----
__global__ __launch_bounds__(512) void bscan(const int* __restrict__ tot,
                                             int* __restrict__ bboff, int nbuck) {
    __shared__ int sc[512];
    int t = threadIdx.x;
    int v = (t < nbuck) ? tot[t] : 0;
    sc[t] = v;
    __syncthreads();
    for (int o = 1; o < 512; o <<= 1) {
        int add = (t >= o) ? sc[t - o] : 0;
        __syncthreads();
        sc[t] += add;
        __syncthreads();
    }
    if (t < nbuck) {
        bboff[t] = sc[t] - v;
        if (t == nbuck - 1) bboff[nbuck] = sc[t];
    }
}

// ---- phase 2c: per-(bucket,chunk) global offsets ----
__global__ __launch_bounds__(512) void rowoff(const int* __restrict__ hist,
                                              const int* __restrict__ bboff,
                                              int* __restrict__ off, int NC, int nbuck) {
    for (int b = threadIdx.x; b < nbuck; b += 512) {
        int run = bboff[b];
        for (int c = 0; c < NC; c++) {
            int v = hist[b * NC + c];
            off[b * NC + c] = run;
            run += v;
        }
    }
}

// ---- phase 3: pack (src,dst) bucket-grouped; LDS cursors, no global atomics ----
__global__ __launch_bounds__(256) void fill2(const int* __restrict__ src,
                                             const int* __restrict__ dst,
                                             const int* __restrict__ off,
                                             int2* __restrict__ binned,
                                             int nE, int NC, int nbuck) {
    __shared__ int cur[MAXBUCK];
    int c = blockIdx.x, t = threadIdx.x;
    for (int i = t; i < nbuck; i += 256) cur[i] = off[i * NC + c];
    __syncthreads();
    int beg = c * CHUNK, end = min(nE, beg + CHUNK);
    for (int e = beg + t; e < end; e += 256) {
        int d = dst[e];
        int pos = atomicAdd(&cur[d >> 8], 1);
        binned[pos] = make_int2(src[e], d);
    }
}

// ---- phase 4: per-bucket count + dinv + cursor + csr scatter (all LDS) ----
__global__ __launch_bounds__(256) void bucket_scat(const int2* __restrict__ binned,
                                                   const int* __restrict__ bboff,
                                                   int* __restrict__ cnt,
                                                   float* __restrict__ dinv,
                                                   int* __restrict__ cursor,
                                                   int* __restrict__ csr_src, int n) {
    __shared__ int2 se[ECAP];
    __shared__ int lcnt[256];
    __shared__ int lcur[256];
    __shared__ int ssc[256];
    int b = blockIdx.x, t = threadIdx.x;
    int node0 = b << 8;
    int nloc = min(256, n - node0);
    int ebeg = bboff[b], eend = bboff[b + 1];
    int ne = eend - ebeg;
    lcnt[t] = 0;
    __syncthreads();
    bool staged = (ne <= ECAP);
    if (staged) {
        for (int i = t; i < ne; i += 256) {
            int2 e = binned[ebeg + i];
            se[i] = e;
            atomicAdd(&lcnt[e.y - node0], 1);
        }
    } else {
        for (int i = t; i < ne; i += 256)
            atomicAdd(&lcnt[binned[ebeg + i].y - node0], 1);
    }
    __syncthreads();
    int myc = (t < nloc) ? lcnt[t] : 0;
    ssc[t] = myc;
    __syncthreads();
    for (int o = 1; o < 256; o <<= 1) {
        int add = (t >= o) ? ssc[t - o] : 0;
        __syncthreads();
        ssc[t] += add;
        __syncthreads();
    }
    int excl = ssc[t] - myc;
    if (t < nloc) {
        cnt[node0 + t] = myc;
        dinv[node0 + t] = rsqrtf((float)(myc + 1));
        cursor[node0 + t] = ebeg + excl;   // cursor = bucket start of node's list
        lcur[t] = excl;
    }
    __syncthreads();
    if (staged) {
        for (int i = t; i < ne; i += 256) {
            int2 e = se[i];
            int pos = atomicAdd(&lcur[e.y - node0], 1);
            csr_src[ebeg + pos] = e.x;
        }
    } else {
        for (int i = t; i < ne; i += 256) {
            int2 e = binned[ebeg + i];
            int pos = atomicAdd(&lcur[e.y - node0], 1);
            csr_src[ebeg + pos] = e.x;
        }
    }
}

// ---- W pre-pack: Wbf[(kb*128+n)*8+j] = bf16(W[(kb*8+j)*128+n]) ----
__global__ __launch_bounds__(256) void wprep(const float* __restrict__ W,
                                             unsigned short* __restrict__ Wbf) {
    int tid = blockIdx.x * 256 + threadIdx.x;   // 16384 threads
    int chunk = tid >> 3, j = tid & 7;
    int kb = chunk >> 7, nn = chunk & 127;
    Wbf[tid] = f2bf(W[(kb * 8 + j) * FEAT + nn]);
}

// ---- MFMA GEMM: gout[N][128](fp8) = bf16(X) @ Wbf * dinv[row] ----
template <bool AFP32>
__global__ __launch_bounds__(256) void gemm_mfma(const void* __restrict__ Xv,
                                                 const unsigned short* __restrict__ Wbf,
                                                 const float* __restrict__ dinv,
                                                 unsigned char* __restrict__ gout,
                                                 int n) {
    int wave = threadIdx.x >> 6, lane = threadIdx.x & 63;
    int m0 = blockIdx.x * 64 + wave * 16;
    if (m0 >= n) return;
    int col = lane & 15, quad = lane >> 4;
    int mc = min(m0 + col, n - 1);

    short8 afr[4];
    if (AFP32) {
        const float* X = (const float*)Xv;
        const float* xr = X + (size_t)mc * FEAT + quad * 8;
#pragma unroll
        for (int ks = 0; ks < 4; ks++) {
            float4 lo = *(const float4*)(xr + ks * 32);
            float4 hi = *(const float4*)(xr + ks * 32 + 4);
            short8 a;
            a[0] = (short)f2bf(lo.x); a[1] = (short)f2bf(lo.y);
            a[2] = (short)f2bf(lo.z); a[3] = (short)f2bf(lo.w);
            a[4] = (short)f2bf(hi.x); a[5] = (short)f2bf(hi.y);
            a[6] = (short)f2bf(hi.z); a[7] = (short)f2bf(hi.w);
            afr[ks] = a;
        }
    } else {
        const int4* X = (const int4*)Xv;
        const int4* xr = X + (size_t)mc * (FEAT / 8) + quad;
#pragma unroll
        for (int ks = 0; ks < 4; ks++) {
            I4S8 u; u.i = xr[ks * 4];
            afr[ks] = u.s;
        }
    }

    float dvr[4];
#pragma unroll
    for (int r = 0; r < 4; r++)
        dvr[r] = dinv[min(m0 + quad * 4 + r, n - 1)];

    const int4* Wb = (const int4*)Wbf;
#pragma unroll
    for (int nt = 0; nt < 8; nt++) {
        float4v acc = {0.f, 0.f, 0.f, 0.f};
#pragma unroll
        for (int ks = 0; ks < 4; ks++) {
            int kb = ks * 4 + quad;
            I4S8 u; u.i = Wb[kb * FEAT + nt * 16 + col];
            acc = __builtin_amdgcn_mfma_f32_16x16x32_bf16(afr[ks], u.s, acc, 0, 0, 0);
        }
#pragma unroll
        for (int r = 0; r < 4; r++) {
            int row = m0 + quad * 4 + r;
            if (row < n)
                gout[(size_t)row * FEAT + nt * 16 + col] = fp8enc(acc[r] * dvr[r]);
        }
    }
}

// ---- fused CSR aggregate + bias + relu. One wave/node, 2 fp8 feats/lane ----
__global__ __launch_bounds__(256) void agg_csr(const int* __restrict__ cursor,
                                               const int* __restrict__ cnt,
                                               const int* __restrict__ csr_src,
                                               const unsigned short* __restrict__ gs,
                                               const float* __restrict__ dinv,
                                               const float* __restrict__ bias,
                                               __hip_bfloat162* __restrict__ outb,
                                               int n) {
    int node = blockIdx.x * 4 + (threadIdx.x >> 6);
    if (node >= n) return;
    int lane = threadIdx.x & 63;

    int beg = cursor[node];           // cursor = list start
    int end = beg + cnt[node];

    floatx2 sl = fp8x2_dec(gs[(size_t)node * 64 + lane]);   // self-loop term
    float ax[4] = {sl.x, 0.f, 0.f, 0.f};
    float ay[4] = {sl.y, 0.f, 0.f, 0.f};

    int j = beg;
    for (; j + 15 < end; j += 16) {
        int sIdx[16];
#pragma unroll
        for (int k = 0; k < 16; k++) sIdx[k] = csr_src[j + k];
        unsigned int uu[16];
#pragma unroll
        for (int k = 0; k < 16; k++) uu[k] = gs[(size_t)sIdx[k] * 64 + lane];
#pragma unroll
        for (int k = 0; k < 16; k++) {
            floatx2 v = fp8x2_dec(uu[k]);
            ax[k & 3] += v.x;
            ay[k & 3] += v.y;
        }
    }
    for (; j + 3 < end; j += 4) {
        int sIdx[4];
#pragma unroll
        for (int k = 0; k < 4; k++) sIdx[k] = csr_src[j + k];
        unsigned int uu[4];
#pragma unroll
        for (int k = 0; k < 4; k++) uu[k] = gs[(size_t)sIdx[k] * 64 + lane];
#pragma unroll
        for (int k = 0; k < 4; k++) {
            floatx2 v = fp8x2_dec(uu[k]);
            ax[k] += v.x;
            ay[k] += v.y;
        }
    }
    for (; j < end; j++) {
        floatx2 v = fp8x2_dec(gs[(size_t)csr_src[j] * 64 + lane]);
        ax[0] += v.x;
        ay[0] += v.y;
    }

    float dv = dinv[node];
    float2 bv = ((const float2*)bias)[lane];
    float sx = (ax[0] + ax[1]) + (ax[2] + ax[3]);
    float sy = (ay[0] + ay[1]) + (ay[2] + ay[3]);
    float2 r;
    r.x = fmaxf(sx * dv + bv.x, 0.0f);
    r.y = fmaxf(sy * dv + bv.y, 0.0f);
    outb[(size_t)node * 64 + lane] = __float22bfloat162_rn(r);
}

// ---- mean pool stage 1 (bf16 input) ----
__global__ __launch_bounds__(256) void pool_kernel(const __hip_bfloat16* __restrict__ a,
                                                   float* __restrict__ pooled, int n) {
    int tid = blockIdx.x * 256 + threadIdx.x;  // 256 blocks -> 65536 threads
    int f = tid & 127;
    int i0 = tid >> 7;  // 0..511
    float s = 0.0f;
    for (int i = i0; i < n; i += 512) s += __bfloat162float(a[(size_t)i * FEAT + f]);
    atomicAdd(&pooled[f], s);
}

// ---- final: out[c] = (pooled/N) . Wc[:,c] + bc[c] ----
__global__ __launch_bounds__(128) void final_kernel(const float* __restrict__ pooled,
                                                    const float* __restrict__ Wc,
                                                    const float* __restrict__ bc,
                                                    float* __restrict__ out,
                                                    int n, int C) {
    __shared__ float p[FEAT];
    int t = threadIdx.x;
    p[t] = pooled[t] * (1.0f / (float)n);
    __syncthreads();
    if (t < C) {
        float acc = bc[t];
        for (int h = 0; h < FEAT; h++)
            acc += p[h] * Wc[h * C + t];
        out[t] = acc;
    }
}

extern "C" void kernel_launch(void* const* d_in, const int* in_sizes, int n_in,
                              void* d_out, int out_size, void* d_ws, size_t ws_size,
                              hipStream_t stream) {
    const float* x  = (const float*)d_in[0];
    const int*   ei = (const int*)d_in[1];
    const float* W1 = (const float*)d_in[2];
    const float* b1 = (const float*)d_in[3];
    const float* W2 = (const float*)d_in[4];
    const float* b2 = (const float*)d_in[5];
    const float* Wc = (const float*)d_in[6];
    const float* bc = (const float*)d_in[7];

    const int N = in_sizes[0] / FEAT;        // 100000
    const int E = in_sizes[1] / 2;           // 1600000
    const int C = out_size;                  // 32
    const int* srcI = ei;
    const int* dstI = ei + E;
    const int NC = (E + CHUNK - 1) / CHUNK;  // edge chunks (98)
    const int NBK = (N + 255) >> 8;          // node buckets (391)

    // workspace carve (256B aligned)
    auto align256 = [](size_t v) { return (v + 255) & ~(size_t)255; };
    char* w = (char*)d_ws;
    int*            cnt     = (int*)w;            w += align256((size_t)N * 4);
    float*          dinv    = (float*)w;          w += align256((size_t)N * 4);
    int*            cursor  = (int*)w;            w += align256((size_t)N * 4);
    int*            csr_src = (int*)w;            w += align256((size_t)E * 4);
    int2*           binned  = (int2*)w;           w += align256((size_t)E * 8);
    int*            hist    = (int*)w;            w += align256((size_t)NBK * NC * 4);
    int*            hoff    = (int*)w;            w += align256((size_t)NBK * NC * 4);
    int*            btot    = (int*)w;            w += align256((size_t)NBK * 4);
    int*            bboff   = (int*)w;            w += align256((size_t)(NBK + 1) * 4);
    unsigned short* Wbf1    = (unsigned short*)w; w += align256((size_t)FEAT * FEAT * 2);
    unsigned short* Wbf2    = (unsigned short*)w; w += align256((size_t)FEAT * FEAT * 2);
    unsigned char*  gbuf    = (unsigned char*)w;  w += align256((size_t)N * FEAT);
    unsigned short* bufA    = (unsigned short*)w; w += align256((size_t)N * FEAT * 2);
    float*          pooled  = (float*)w;          w += align256((size_t)FEAT * 4);

    hipMemsetAsync(pooled, 0, (size_t)FEAT * 4, stream);

    // W pre-pack (tiny)
    wprep<<<64, 256, 0, stream>>>(W1, Wbf1);
    wprep<<<64, 256, 0, stream>>>(W2, Wbf2);

    // ---- atomic-free CSR build ----
    hist2<<<NC, 256, 0, stream>>>(dstI, hist, E, NC, NBK);
    rowsum<<<1, 512, 0, stream>>>(hist, btot, NC, NBK);
    bscan<<<1, 512, 0, stream>>>(btot, bboff, NBK);
    rowoff<<<1, 512, 0, stream>>>(hist, bboff, hoff, NC, NBK);
    fill2<<<NC, 256, 0, stream>>>(srcI, dstI, hoff, binned, E, NC, NBK);
    bucket_scat<<<NBK, 256, 0, stream>>>(binned, bboff, cnt, dinv, cursor, csr_src, N);

    const int gAgg = (N + 3) / 4;
    const int gGemm = (N + 63) / 64;

    // ---- layer 1 ----
    gemm_mfma<true><<<gGemm, 256, 0, stream>>>(x, Wbf1, dinv, gbuf, N);
    agg_csr<<<gAgg, 256, 0, stream>>>(cursor, cnt, csr_src,
                                      (const unsigned short*)gbuf, dinv, b1,
                                      (__hip_bfloat162*)bufA, N);

    // ---- layer 2 ----
    gemm_mfma<false><<<gGemm, 256, 0, stream>>>(bufA, Wbf2, dinv, gbuf, N);
    agg_csr<<<gAgg, 256, 0, stream>>>(cursor, cnt, csr_src,
                                      (const unsigned short*)gbuf, dinv, b2,
                                      (__hip_bfloat162*)bufA, N);

    // ---- pool + classifier ----
    pool_kernel<<<256, 256, 0, stream>>>((const __hip_bfloat16*)bufA, pooled, N);
    final_kernel<<<1, 128, 0, stream>>>(pooled, Wc, bc, (float*)d_out, N, C);
}

// Round 10
// 458.430 us; speedup vs baseline: 1.1461x; 1.0046x over previous
//
#include <hip/hip_runtime.h>
#include <hip/hip_bf16.h>

// GCN: h1 = relu(Agg(x@W1)+b1); h2 = relu(Agg(h1@W2)+b2); out = mean(h2)@Wc + bc
// Agg via CSR gather; g = (X@W)*dinv stored OCP fp8 e4m3 (128B rows).
// CSR build atomic-free (LDS histograms/cursors; global atomics write through
// EA ~16-40B each — measured r2/r8). binned packs (src<<8 | dst&255) in 1 int.
// Layer-2 agg fuses the mean-pool: h2 never materialized (only consumer is
// pooling), 128 global atomics per 64-node block.
// GEMMs: mfma_f32_16x16x32_bf16, LDS-free, W pre-packed to k-block layout.

#define FEAT 128
#define CHUNK 16384     // edges per chunk
#define MAXBUCK 512     // max node-buckets (N <= 131072)
#define ECAP 12288      // LDS edge staging cap in bucket_scat (48 KB of int)

typedef __attribute__((ext_vector_type(8))) short short8;
typedef __attribute__((ext_vector_type(4))) float float4v;
typedef __attribute__((ext_vector_type(2))) float floatx2;

union I4S8 { int4 i; short8 s; };

static __device__ inline unsigned short f2bf(float f) {
    union { __hip_bfloat16 h; unsigned short u; } cv;
    cv.h = __float2bfloat16(f);
    return cv.u;
}

// ---- OCP fp8 e4m3 helpers ----
static __device__ inline floatx2 fp8x2_dec(unsigned int u) {
#if __has_builtin(__builtin_amdgcn_cvt_pk_f32_fp8)
    return __builtin_amdgcn_cvt_pk_f32_fp8((int)u, false);
#else
    floatx2 r;
    unsigned int b0 = u & 0xFFu, b1 = (u >> 8) & 0xFFu;
    r.x = __uint_as_float(((b0 & 0x80u) << 24) | ((b0 & 0x7Fu) << 20)) * 0x1p+120f;
    r.y = __uint_as_float(((b1 & 0x80u) << 24) | ((b1 & 0x7Fu) << 20)) * 0x1p+120f;
    return r;
#endif
}

static __device__ inline unsigned char fp8enc(float f) {
#if __has_builtin(__builtin_amdgcn_cvt_pk_fp8_f32)
    return (unsigned char)(__builtin_amdgcn_cvt_pk_fp8_f32(f, 0.0f, 0, false) & 0xFF);
#else
    unsigned int u = __float_as_uint(f);
    unsigned int s = (u >> 24) & 0x80u;
    float a = fabsf(f);
    a = fminf(a, 448.0f);
    unsigned int code;
    if (a < 0.015625f) {
        code = (unsigned int)(int)rintf(a * 512.0f);
    } else {
        unsigned int au = __float_as_uint(a);
        unsigned int r = au + 0x0007FFFFu + ((au >> 20) & 1u);
        unsigned int e = (r >> 23) - 120u;
        unsigned int m = (r >> 20) & 7u;
        code = (e << 3) | m;
        if (code > 0x7Eu) code = 0x7Eu;
    }
    return (unsigned char)(code | s);
#endif
}

// ---- build phase 1: per-chunk histogram over node buckets (dst>>8) ----
__global__ __launch_bounds__(256) void hist2(const int* __restrict__ dst,
                                             int* __restrict__ hist,
                                             int nE, int NC, int nbuck) {
    __shared__ int h[MAXBUCK];
    int c = blockIdx.x, t = threadIdx.x;
    for (int i = t; i < nbuck; i += 256) h[i] = 0;
    __syncthreads();
    int beg = c * CHUNK, end = min(nE, beg + CHUNK);
    for (int e = beg + t; e < end; e += 256)
        atomicAdd(&h[dst[e] >> 8], 1);
    __syncthreads();
    for (int i = t; i < nbuck; i += 256) hist[i * NC + c] = h[i];
}

// ---- phase 2 (fused): bucket totals -> exclusive scan -> per-chunk offsets ----
__global__ __launch_bounds__(512) void bucket_offsets(const int* __restrict__ hist,
                                                      int* __restrict__ hoff,
                                                      int* __restrict__ bboff,
                                                      int NC, int nbuck) {
    __shared__ int sc[512];
    int t = threadIdx.x;
    int tot = 0;
    if (t < nbuck)
        for (int c = 0; c < NC; c++) tot += hist[t * NC + c];
    sc[t] = tot;
    __syncthreads();
    for (int o = 1; o < 512; o <<= 1) {
        int add = (t >= o) ? sc[t - o] : 0;
        __syncthreads();
        sc[t] += add;
        __syncthreads();
    }
    int excl = sc[t] - tot;
    if (t < nbuck) {
        bboff[t] = excl;
        if (t == nbuck - 1) bboff[nbuck] = sc[t];
        int run = excl;
        for (int c = 0; c < NC; c++) {
            int v = hist[t * NC + c];
            hoff[t * NC + c] = run;
            run += v;
        }
    }
}

// ---- phase 3: pack (src<<8|dloc) bucket-grouped; LDS cursors ----
__global__ __launch_bounds__(256) void fill2(const int* __restrict__ src,
                                             const int* __restrict__ dst,
                                             const int* __restrict__ off,
                                             int* __restrict__ binned,
                                             int nE, int NC, int nbuck) {
    __shared__ int cur[MAXBUCK];
    int c = blockIdx.x, t = threadIdx.x;
    for (int i = t; i < nbuck; i += 256) cur[i] = off[i * NC + c];
    __syncthreads();
    int beg = c * CHUNK, end = min(nE, beg + CHUNK);
    for (int e = beg + t; e < end; e += 256) {
        int d = dst[e];
        int pos = atomicAdd(&cur[d >> 8], 1);
        binned[pos] = (src[e] << 8) | (d & 255);
    }
}

// ---- phase 4: per-bucket count + dinv + cursor + csr scatter (all LDS) ----
__global__ __launch_bounds__(256) void bucket_scat(const int* __restrict__ binned,
                                                   const int* __restrict__ bboff,
                                                   int* __restrict__ cnt,
                                                   float* __restrict__ dinv,
                                                   int* __restrict__ cursor,
                                                   int* __restrict__ csr_src, int n) {
    __shared__ int se[ECAP];
    __shared__ int lcnt[256];
    __shared__ int lcur[256];
    __shared__ int ssc[256];
    int b = blockIdx.x, t = threadIdx.x;
    int node0 = b << 8;
    int nloc = min(256, n - node0);
    int ebeg = bboff[b], eend = bboff[b + 1];
    int ne = eend - ebeg;
    lcnt[t] = 0;
    __syncthreads();
    bool staged = (ne <= ECAP);
    if (staged) {
        for (int i = t; i < ne; i += 256) {
            int e = binned[ebeg + i];
            se[i] = e;
            atomicAdd(&lcnt[e & 255], 1);
        }
    } else {
        for (int i = t; i < ne; i += 256)
            atomicAdd(&lcnt[binned[ebeg + i] & 255], 1);
    }
    __syncthreads();
    int myc = (t < nloc) ? lcnt[t] : 0;
    ssc[t] = myc;
    __syncthreads();
    for (int o = 1; o < 256; o <<= 1) {
        int add = (t >= o) ? ssc[t - o] : 0;
        __syncthreads();
        ssc[t] += add;
        __syncthreads();
    }
    int excl = ssc[t] - myc;
    if (t < nloc) {
        cnt[node0 + t] = myc;
        dinv[node0 + t] = rsqrtf((float)(myc + 1));
        cursor[node0 + t] = ebeg + excl;   // cursor = start of node's list
        lcur[t] = excl;
    }
    __syncthreads();
    if (staged) {
        for (int i = t; i < ne; i += 256) {
            int e = se[i];
            int pos = atomicAdd(&lcur[e & 255], 1);
            csr_src[ebeg + pos] = ((unsigned int)e) >> 8;
        }
    } else {
        for (int i = t; i < ne; i += 256) {
            int e = binned[ebeg + i];
            int pos = atomicAdd(&lcur[e & 255], 1);
            csr_src[ebeg + pos] = ((unsigned int)e) >> 8;
        }
    }
}

// ---- W pre-pack (both layers): Wbf[(kb*128+n)*8+j] = bf16(W[(kb*8+j)*128+n]) ----
__global__ __launch_bounds__(256) void wprep2(const float* __restrict__ W1,
                                              const float* __restrict__ W2,
                                              unsigned short* __restrict__ Wbf1,
                                              unsigned short* __restrict__ Wbf2) {
    int tid = blockIdx.x * 256 + threadIdx.x;   // 32768 threads
    const float* W = (tid < 16384) ? W1 : W2;
    unsigned short* O = (tid < 16384) ? Wbf1 : Wbf2;
    int id = tid & 16383;
    int chunk = id >> 3, j = id & 7;
    int kb = chunk >> 7, nn = chunk & 127;
    O[id] = f2bf(W[(kb * 8 + j) * FEAT + nn]);
}

// ---- MFMA GEMM: gout[N][128](fp8) = bf16(X) @ Wbf * dinv[row] ----
template <bool AFP32>
__global__ __launch_bounds__(256) void gemm_mfma(const void* __restrict__ Xv,
                                                 const unsigned short* __restrict__ Wbf,
                                                 const float* __restrict__ dinv,
                                                 unsigned char* __restrict__ gout,
                                                 int n) {
    int wave = threadIdx.x >> 6, lane = threadIdx.x & 63;
    int m0 = blockIdx.x * 64 + wave * 16;
    if (m0 >= n) return;
    int col = lane & 15, quad = lane >> 4;
    int mc = min(m0 + col, n - 1);

    short8 afr[4];
    if (AFP32) {
        const float* X = (const float*)Xv;
        const float* xr = X + (size_t)mc * FEAT + quad * 8;
#pragma unroll
        for (int ks = 0; ks < 4; ks++) {
            float4 lo = *(const float4*)(xr + ks * 32);
            float4 hi = *(const float4*)(xr + ks * 32 + 4);
            short8 a;
            a[0] = (short)f2bf(lo.x); a[1] = (short)f2bf(lo.y);
            a[2] = (short)f2bf(lo.z); a[3] = (short)f2bf(lo.w);
            a[4] = (short)f2bf(hi.x); a[5] = (short)f2bf(hi.y);
            a[6] = (short)f2bf(hi.z); a[7] = (short)f2bf(hi.w);
            afr[ks] = a;
        }
    } else {
        const int4* X = (const int4*)Xv;
        const int4* xr = X + (size_t)mc * (FEAT / 8) + quad;
#pragma unroll
        for (int ks = 0; ks < 4; ks++) {
            I4S8 u; u.i = xr[ks * 4];
            afr[ks] = u.s;
        }
    }

    float dvr[4];
#pragma unroll
    for (int r = 0; r < 4; r++)
        dvr[r] = dinv[min(m0 + quad * 4 + r, n - 1)];

    const int4* Wb = (const int4*)Wbf;
#pragma unroll
    for (int nt = 0; nt < 8; nt++) {
        float4v acc = {0.f, 0.f, 0.f, 0.f};
#pragma unroll
        for (int ks = 0; ks < 4; ks++) {
            int kb = ks * 4 + quad;
            I4S8 u; u.i = Wb[kb * FEAT + nt * 16 + col];
            acc = __builtin_amdgcn_mfma_f32_16x16x32_bf16(afr[ks], u.s, acc, 0, 0, 0);
        }
#pragma unroll
        for (int r = 0; r < 4; r++) {
            int row = m0 + quad * 4 + r;
            if (row < n)
                gout[(size_t)row * FEAT + nt * 16 + col] = fp8enc(acc[r] * dvr[r]);
        }
    }
}

// ---- gather-sum core for one node (fp8 rows, 2 feats/lane) ----
static __device__ inline void gather_node(const int* __restrict__ csr_src,
                                          const unsigned short* __restrict__ gs,
                                          int beg, int end, int node, int lane,
                                          float& sx, float& sy) {
    floatx2 sl = fp8x2_dec(gs[(size_t)node * 64 + lane]);   // self-loop term
    float ax[4] = {sl.x, 0.f, 0.f, 0.f};
    float ay[4] = {sl.y, 0.f, 0.f, 0.f};
    int j = beg;
    for (; j + 15 < end; j += 16) {
        int sIdx[16];
#pragma unroll
        for (int k = 0; k < 16; k++) sIdx[k] = csr_src[j + k];
        unsigned int uu[16];
#pragma unroll
        for (int k = 0; k < 16; k++) uu[k] = gs[(size_t)sIdx[k] * 64 + lane];
#pragma unroll
        for (int k = 0; k < 16; k++) {
            floatx2 v = fp8x2_dec(uu[k]);
            ax[k & 3] += v.x;
            ay[k & 3] += v.y;
        }
    }
    for (; j + 3 < end; j += 4) {
        int sIdx[4];
#pragma unroll
        for (int k = 0; k < 4; k++) sIdx[k] = csr_src[j + k];
        unsigned int uu[4];
#pragma unroll
        for (int k = 0; k < 4; k++) uu[k] = gs[(size_t)sIdx[k] * 64 + lane];
#pragma unroll
        for (int k = 0; k < 4; k++) {
            floatx2 v = fp8x2_dec(uu[k]);
            ax[k] += v.x;
            ay[k] += v.y;
        }
    }
    for (; j < end; j++) {
        floatx2 v = fp8x2_dec(gs[(size_t)csr_src[j] * 64 + lane]);
        ax[0] += v.x;
        ay[0] += v.y;
    }
    sx = (ax[0] + ax[1]) + (ax[2] + ax[3]);
    sy = (ay[0] + ay[1]) + (ay[2] + ay[3]);
}

// ---- layer-1 agg: CSR gather + bias + relu -> bf16 rows ----
__global__ __launch_bounds__(256) void agg_csr(const int* __restrict__ cursor,
                                               const int* __restrict__ cnt,
                                               const int* __restrict__ csr_src,
                                               const unsigned short* __restrict__ gs,
                                               const float* __restrict__ dinv,
                                               const float* __restrict__ bias,
                                               __hip_bfloat162* __restrict__ outb,
                                               int n) {
    int node = blockIdx.x * 4 + (threadIdx.x >> 6);
    if (node >= n) return;
    int lane = threadIdx.x & 63;
    int beg = cursor[node];
    int end = beg + cnt[node];
    float sx, sy;
    gather_node(csr_src, gs, beg, end, node, lane, sx, sy);
    float dv = dinv[node];
    float2 bv = ((const float2*)bias)[lane];
    float2 r;
    r.x = fmaxf(sx * dv + bv.x, 0.0f);
    r.y = fmaxf(sy * dv + bv.y, 0.0f);
    outb[(size_t)node * 64 + lane] = __float22bfloat162_rn(r);
}

// ---- layer-2 agg fused with mean pool: h2 never materialized ----
// Block covers 64 nodes (4 waves x 16 serial); LDS reduce; 128 atomics/block.
__global__ __launch_bounds__(256) void agg_pool(const int* __restrict__ cursor,
                                                const int* __restrict__ cnt,
                                                const int* __restrict__ csr_src,
                                                const unsigned short* __restrict__ gs,
                                                const float* __restrict__ dinv,
                                                const float* __restrict__ bias,
                                                float* __restrict__ pooled, int n) {
    __shared__ float psx[64];
    __shared__ float psy[64];
    int wave = threadIdx.x >> 6, lane = threadIdx.x & 63;
    if (threadIdx.x < 64) { psx[threadIdx.x] = 0.f; psy[threadIdx.x] = 0.f; }
    __syncthreads();
    float2 bv = ((const float2*)bias)[lane];
    float px = 0.f, py = 0.f;
    int base = blockIdx.x * 64 + wave * 16;
    for (int i = 0; i < 16; i++) {
        int node = base + i;
        if (node >= n) break;
        int beg = cursor[node];
        int end = beg + cnt[node];
        float sx, sy;
        gather_node(csr_src, gs, beg, end, node, lane, sx, sy);
        float dv = dinv[node];
        px += fmaxf(sx * dv + bv.x, 0.0f);
        py += fmaxf(sy * dv + bv.y, 0.0f);
    }
    atomicAdd(&psx[lane], px);
    atomicAdd(&psy[lane], py);
    __syncthreads();
    if (threadIdx.x < 64) {
        atomicAdd(&pooled[2 * threadIdx.x + 0], psx[threadIdx.x]);
        atomicAdd(&pooled[2 * threadIdx.x + 1], psy[threadIdx.x]);
    }
}

// ---- final: out[c] = (pooled/N) . Wc[:,c] + bc[c] ----
__global__ __launch_bounds__(128) void final_kernel(const float* __restrict__ pooled,
                                                    const float* __restrict__ Wc,
                                                    const float* __restrict__ bc,
                                                    float* __restrict__ out,
                                                    int n, int C) {
    __shared__ float p[FEAT];
    int t = threadIdx.x;
    p[t] = pooled[t] * (1.0f / (float)n);
    __syncthreads();
    if (t < C) {
        float acc = bc[t];
        for (int h = 0; h < FEAT; h++)
            acc += p[h] * Wc[h * C + t];
        out[t] = acc;
    }
}

extern "C" void kernel_launch(void* const* d_in, const int* in_sizes, int n_in,
                              void* d_out, int out_size, void* d_ws, size_t ws_size,
                              hipStream_t stream) {
    const float* x  = (const float*)d_in[0];
    const int*   ei = (const int*)d_in[1];
    const float* W1 = (const float*)d_in[2];
    const float* b1 = (const float*)d_in[3];
    const float* W2 = (const float*)d_in[4];
    const float* b2 = (const float*)d_in[5];
    const float* Wc = (const float*)d_in[6];
    const float* bc = (const float*)d_in[7];

    const int N = in_sizes[0] / FEAT;        // 100000
    const int E = in_sizes[1] / 2;           // 1600000
    const int C = out_size;                  // 32
    const int* srcI = ei;
    const int* dstI = ei + E;
    const int NC = (E + CHUNK - 1) / CHUNK;  // edge chunks (98)
    const int NBK = (N + 255) >> 8;          // node buckets (391, <= MAXBUCK)

    // workspace carve (256B aligned)
    auto align256 = [](size_t v) { return (v + 255) & ~(size_t)255; };
    char* w = (char*)d_ws;
    int*            cnt     = (int*)w;            w += align256((size_t)N * 4);
    float*          dinv    = (float*)w;          w += align256((size_t)N * 4);
    int*            cursor  = (int*)w;            w += align256((size_t)N * 4);
    int*            csr_src = (int*)w;            w += align256((size_t)E * 4);
    int*            binned  = (int*)w;            w += align256((size_t)E * 4);
    int*            hist    = (int*)w;            w += align256((size_t)NBK * NC * 4);
    int*            hoff    = (int*)w;            w += align256((size_t)NBK * NC * 4);
    int*            bboff   = (int*)w;            w += align256((size_t)(NBK + 1) * 4);
    unsigned short* Wbf1    = (unsigned short*)w; w += align256((size_t)FEAT * FEAT * 2);
    unsigned short* Wbf2    = (unsigned short*)w; w += align256((size_t)FEAT * FEAT * 2);
    unsigned char*  gbuf    = (unsigned char*)w;  w += align256((size_t)N * FEAT);
    unsigned short* bufA    = (unsigned short*)w; w += align256((size_t)N * FEAT * 2);
    float*          pooled  = (float*)w;          w += align256((size_t)FEAT * 4);

    hipMemsetAsync(pooled, 0, (size_t)FEAT * 4, stream);

    // W pre-pack (both layers, one launch)
    wprep2<<<128, 256, 0, stream>>>(W1, W2, Wbf1, Wbf2);

    // ---- atomic-free CSR build ----
    hist2<<<NC, 256, 0, stream>>>(dstI, hist, E, NC, NBK);
    bucket_offsets<<<1, 512, 0, stream>>>(hist, hoff, bboff, NC, NBK);
    fill2<<<NC, 256, 0, stream>>>(srcI, dstI, hoff, binned, E, NC, NBK);
    bucket_scat<<<NBK, 256, 0, stream>>>(binned, bboff, cnt, dinv, cursor, csr_src, N);

    const int gGemm = (N + 63) / 64;

    // ---- layer 1 ----
    gemm_mfma<true><<<gGemm, 256, 0, stream>>>(x, Wbf1, dinv, gbuf, N);
    agg_csr<<<(N + 3) / 4, 256, 0, stream>>>(cursor, cnt, csr_src,
                                             (const unsigned short*)gbuf, dinv, b1,
                                             (__hip_bfloat162*)bufA, N);

    // ---- layer 2 (agg fused with mean pool) ----
    gemm_mfma<false><<<gGemm, 256, 0, stream>>>(bufA, Wbf2, dinv, gbuf, N);
    agg_pool<<<(N + 63) / 64, 256, 0, stream>>>(cursor, cnt, csr_src,
                                                (const unsigned short*)gbuf, dinv, b2,
                                                pooled, N);

    // ---- classifier ----
    final_kernel<<<1, 128, 0, stream>>>(pooled, Wc, bc, (float*)d_out, N, C);
}

// Round 11
// 451.470 us; speedup vs baseline: 1.1638x; 1.0154x over previous
//
#include <hip/hip_runtime.h>
#include <hip/hip_bf16.h>

// GCN: h1 = relu(Agg(x@W1)+b1); h2 = relu(Agg(h1@W2)+b2); out = mean(h2)@Wc + bc
// Agg via CSR gather; g = (X@W)*dinv stored OCP fp8 e4m3 (128B rows).
// CSR build atomic-free (LDS histograms/cursors). binned packs (src<<8|dst&255).
// Layer-2 agg is NOT fused with pool (r10 A/B: 16-serial-node fusion lost 2x to
// latency-hiding collapse — 6.3k waves can't hide random-gather latency; the
// 1-node-per-wave form at 100k waves runs 64 us).
// GEMMs: mfma_f32_16x16x32_bf16, LDS-free, W pre-packed to k-block layout.

#define FEAT 128
#define CHUNK 16384     // edges per chunk
#define MAXBUCK 512     // max node-buckets (N <= 131072)
#define ECAP 12288      // LDS edge staging cap in bucket_scat (48 KB of int)

typedef __attribute__((ext_vector_type(8))) short short8;
typedef __attribute__((ext_vector_type(4))) float float4v;
typedef __attribute__((ext_vector_type(2))) float floatx2;

union I4S8 { int4 i; short8 s; };

static __device__ inline unsigned short f2bf(float f) {
    union { __hip_bfloat16 h; unsigned short u; } cv;
    cv.h = __float2bfloat16(f);
    return cv.u;
}

// ---- OCP fp8 e4m3 helpers ----
static __device__ inline floatx2 fp8x2_dec(unsigned int u) {
#if __has_builtin(__builtin_amdgcn_cvt_pk_f32_fp8)
    return __builtin_amdgcn_cvt_pk_f32_fp8((int)u, false);
#else
    floatx2 r;
    unsigned int b0 = u & 0xFFu, b1 = (u >> 8) & 0xFFu;
    r.x = __uint_as_float(((b0 & 0x80u) << 24) | ((b0 & 0x7Fu) << 20)) * 0x1p+120f;
    r.y = __uint_as_float(((b1 & 0x80u) << 24) | ((b1 & 0x7Fu) << 20)) * 0x1p+120f;
    return r;
#endif
}

static __device__ inline unsigned char fp8enc(float f) {
#if __has_builtin(__builtin_amdgcn_cvt_pk_fp8_f32)
    return (unsigned char)(__builtin_amdgcn_cvt_pk_fp8_f32(f, 0.0f, 0, false) & 0xFF);
#else
    unsigned int u = __float_as_uint(f);
    unsigned int s = (u >> 24) & 0x80u;
    float a = fabsf(f);
    a = fminf(a, 448.0f);
    unsigned int code;
    if (a < 0.015625f) {
        code = (unsigned int)(int)rintf(a * 512.0f);
    } else {
        unsigned int au = __float_as_uint(a);
        unsigned int r = au + 0x0007FFFFu + ((au >> 20) & 1u);
        unsigned int e = (r >> 23) - 120u;
        unsigned int m = (r >> 20) & 7u;
        code = (e << 3) | m;
        if (code > 0x7Eu) code = 0x7Eu;
    }
    return (unsigned char)(code | s);
#endif
}

// ---- build phase 1: per-chunk histogram over node buckets (dst>>8) ----
__global__ __launch_bounds__(256) void hist2(const int* __restrict__ dst,
                                             int* __restrict__ hist,
                                             int nE, int NC, int nbuck) {
    __shared__ int h[MAXBUCK];
    int c = blockIdx.x, t = threadIdx.x;
    for (int i = t; i < nbuck; i += 256) h[i] = 0;
    __syncthreads();
    int beg = c * CHUNK, end = min(nE, beg + CHUNK);
    for (int e = beg + t; e < end; e += 256)
        atomicAdd(&h[dst[e] >> 8], 1);
    __syncthreads();
    for (int i = t; i < nbuck; i += 256) hist[i * NC + c] = h[i];
}

// ---- phase 2 (fused): bucket totals -> exclusive scan -> per-chunk offsets ----
__global__ __launch_bounds__(512) void bucket_offsets(const int* __restrict__ hist,
                                                      int* __restrict__ hoff,
                                                      int* __restrict__ bboff,
                                                      int NC, int nbuck) {
    __shared__ int sc[512];
    int t = threadIdx.x;
    int tot = 0;
    if (t < nbuck)
        for (int c = 0; c < NC; c++) tot += hist[t * NC + c];
    sc[t] = tot;
    __syncthreads();
    for (int o = 1; o < 512; o <<= 1) {
        int add = (t >= o) ? sc[t - o] : 0;
        __syncthreads();
        sc[t] += add;
        __syncthreads();
    }
    int excl = sc[t] - tot;
    if (t < nbuck) {
        bboff[t] = excl;
        if (t == nbuck - 1) bboff[nbuck] = sc[t];
        int run = excl;
        for (int c = 0; c < NC; c++) {
            int v = hist[t * NC + c];
            hoff[t * NC + c] = run;
            run += v;
        }
    }
}

// ---- phase 3: pack (src<<8|dloc) bucket-grouped; LDS cursors ----
__global__ __launch_bounds__(256) void fill2(const int* __restrict__ src,
                                             const int* __restrict__ dst,
                                             const int* __restrict__ off,
                                             int* __restrict__ binned,
                                             int nE, int NC, int nbuck) {
    __shared__ int cur[MAXBUCK];
    int c = blockIdx.x, t = threadIdx.x;
    for (int i = t; i < nbuck; i += 256) cur[i] = off[i * NC + c];
    __syncthreads();
    int beg = c * CHUNK, end = min(nE, beg + CHUNK);
    for (int e = beg + t; e < end; e += 256) {
        int d = dst[e];
        int pos = atomicAdd(&cur[d >> 8], 1);
        binned[pos] = (src[e] << 8) | (d & 255);
    }
}

// ---- phase 4: per-bucket count + dinv + cursor + csr scatter (all LDS) ----
__global__ __launch_bounds__(256) void bucket_scat(const int* __restrict__ binned,
                                                   const int* __restrict__ bboff,
                                                   int* __restrict__ cnt,
                                                   float* __restrict__ dinv,
                                                   int* __restrict__ cursor,
                                                   int* __restrict__ csr_src, int n) {
    __shared__ int se[ECAP];
    __shared__ int lcnt[256];
    __shared__ int lcur[256];
    __shared__ int ssc[256];
    int b = blockIdx.x, t = threadIdx.x;
    int node0 = b << 8;
    int nloc = min(256, n - node0);
    int ebeg = bboff[b], eend = bboff[b + 1];
    int ne = eend - ebeg;
    lcnt[t] = 0;
    __syncthreads();
    bool staged = (ne <= ECAP);
    if (staged) {
        for (int i = t; i < ne; i += 256) {
            int e = binned[ebeg + i];
            se[i] = e;
            atomicAdd(&lcnt[e & 255], 1);
        }
    } else {
        for (int i = t; i < ne; i += 256)
            atomicAdd(&lcnt[binned[ebeg + i] & 255], 1);
    }
    __syncthreads();
    int myc = (t < nloc) ? lcnt[t] : 0;
    ssc[t] = myc;
    __syncthreads();
    for (int o = 1; o < 256; o <<= 1) {
        int add = (t >= o) ? ssc[t - o] : 0;
        __syncthreads();
        ssc[t] += add;
        __syncthreads();
    }
    int excl = ssc[t] - myc;
    if (t < nloc) {
        cnt[node0 + t] = myc;
        dinv[node0 + t] = rsqrtf((float)(myc + 1));
        cursor[node0 + t] = ebeg + excl;   // cursor = start of node's list
        lcur[t] = excl;
    }
    __syncthreads();
    if (staged) {
        for (int i = t; i < ne; i += 256) {
            int e = se[i];
            int pos = atomicAdd(&lcur[e & 255], 1);
            csr_src[ebeg + pos] = ((unsigned int)e) >> 8;
        }
    } else {
        for (int i = t; i < ne; i += 256) {
            int e = binned[ebeg + i];
            int pos = atomicAdd(&lcur[e & 255], 1);
            csr_src[ebeg + pos] = ((unsigned int)e) >> 8;
        }
    }
}

// ---- W pre-pack (both layers): Wbf[(kb*128+n)*8+j] = bf16(W[(kb*8+j)*128+n]) ----
__global__ __launch_bounds__(256) void wprep2(const float* __restrict__ W1,
                                              const float* __restrict__ W2,
                                              unsigned short* __restrict__ Wbf1,
                                              unsigned short* __restrict__ Wbf2) {
    int tid = blockIdx.x * 256 + threadIdx.x;   // 32768 threads
    const float* W = (tid < 16384) ? W1 : W2;
    unsigned short* O = (tid < 16384) ? Wbf1 : Wbf2;
    int id = tid & 16383;
    int chunk = id >> 3, j = id & 7;
    int kb = chunk >> 7, nn = chunk & 127;
    O[id] = f2bf(W[(kb * 8 + j) * FEAT + nn]);
}

// ---- MFMA GEMM: gout[N][128](fp8) = bf16(X) @ Wbf * dinv[row] ----
template <bool AFP32>
__global__ __launch_bounds__(256) void gemm_mfma(const void* __restrict__ Xv,
                                                 const unsigned short* __restrict__ Wbf,
                                                 const float* __restrict__ dinv,
                                                 unsigned char* __restrict__ gout,
                                                 int n) {
    int wave = threadIdx.x >> 6, lane = threadIdx.x & 63;
    int m0 = blockIdx.x * 64 + wave * 16;
    if (m0 >= n) return;
    int col = lane & 15, quad = lane >> 4;
    int mc = min(m0 + col, n - 1);

    short8 afr[4];
    if (AFP32) {
        const float* X = (const float*)Xv;
        const float* xr = X + (size_t)mc * FEAT + quad * 8;
#pragma unroll
        for (int ks = 0; ks < 4; ks++) {
            float4 lo = *(const float4*)(xr + ks * 32);
            float4 hi = *(const float4*)(xr + ks * 32 + 4);
            short8 a;
            a[0] = (short)f2bf(lo.x); a[1] = (short)f2bf(lo.y);
            a[2] = (short)f2bf(lo.z); a[3] = (short)f2bf(lo.w);
            a[4] = (short)f2bf(hi.x); a[5] = (short)f2bf(hi.y);
            a[6] = (short)f2bf(hi.z); a[7] = (short)f2bf(hi.w);
            afr[ks] = a;
        }
    } else {
        const int4* X = (const int4*)Xv;
        const int4* xr = X + (size_t)mc * (FEAT / 8) + quad;
#pragma unroll
        for (int ks = 0; ks < 4; ks++) {
            I4S8 u; u.i = xr[ks * 4];
            afr[ks] = u.s;
        }
    }

    float dvr[4];
#pragma unroll
    for (int r = 0; r < 4; r++)
        dvr[r] = dinv[min(m0 + quad * 4 + r, n - 1)];

    const int4* Wb = (const int4*)Wbf;
#pragma unroll
    for (int nt = 0; nt < 8; nt++) {
        float4v acc = {0.f, 0.f, 0.f, 0.f};
#pragma unroll
        for (int ks = 0; ks < 4; ks++) {
            int kb = ks * 4 + quad;
            I4S8 u; u.i = Wb[kb * FEAT + nt * 16 + col];
            acc = __builtin_amdgcn_mfma_f32_16x16x32_bf16(afr[ks], u.s, acc, 0, 0, 0);
        }
#pragma unroll
        for (int r = 0; r < 4; r++) {
            int row = m0 + quad * 4 + r;
            if (row < n)
                gout[(size_t)row * FEAT + nt * 16 + col] = fp8enc(acc[r] * dvr[r]);
        }
    }
}

// ---- gather-sum core for one node (fp8 rows, 2 feats/lane) ----
static __device__ inline void gather_node(const int* __restrict__ csr_src,
                                          const unsigned short* __restrict__ gs,
                                          int beg, int end, int node, int lane,
                                          float& sx, float& sy) {
    floatx2 sl = fp8x2_dec(gs[(size_t)node * 64 + lane]);   // self-loop term
    float ax[4] = {sl.x, 0.f, 0.f, 0.f};
    float ay[4] = {sl.y, 0.f, 0.f, 0.f};
    int j = beg;
    for (; j + 15 < end; j += 16) {
        int sIdx[16];
#pragma unroll
        for (int k = 0; k < 16; k++) sIdx[k] = csr_src[j + k];
        unsigned int uu[16];
#pragma unroll
        for (int k = 0; k < 16; k++) uu[k] = gs[(size_t)sIdx[k] * 64 + lane];
#pragma unroll
        for (int k = 0; k < 16; k++) {
            floatx2 v = fp8x2_dec(uu[k]);
            ax[k & 3] += v.x;
            ay[k & 3] += v.y;
        }
    }
    for (; j + 3 < end; j += 4) {
        int sIdx[4];
#pragma unroll
        for (int k = 0; k < 4; k++) sIdx[k] = csr_src[j + k];
        unsigned int uu[4];
#pragma unroll
        for (int k = 0; k < 4; k++) uu[k] = gs[(size_t)sIdx[k] * 64 + lane];
#pragma unroll
        for (int k = 0; k < 4; k++) {
            floatx2 v = fp8x2_dec(uu[k]);
            ax[k] += v.x;
            ay[k] += v.y;
        }
    }
    for (; j < end; j++) {
        floatx2 v = fp8x2_dec(gs[(size_t)csr_src[j] * 64 + lane]);
        ax[0] += v.x;
        ay[0] += v.y;
    }
    sx = (ax[0] + ax[1]) + (ax[2] + ax[3]);
    sy = (ay[0] + ay[1]) + (ay[2] + ay[3]);
}

// ---- agg: CSR gather + bias + relu -> bf16 rows (1 node per wave) ----
__global__ __launch_bounds__(256) void agg_csr(const int* __restrict__ cursor,
                                               const int* __restrict__ cnt,
                                               const int* __restrict__ csr_src,
                                               const unsigned short* __restrict__ gs,
                                               const float* __restrict__ dinv,
                                               const float* __restrict__ bias,
                                               __hip_bfloat162* __restrict__ outb,
                                               int n) {
    int node = blockIdx.x * 4 + (threadIdx.x >> 6);
    if (node >= n) return;
    int lane = threadIdx.x & 63;
    int beg = cursor[node];
    int end = beg + cnt[node];
    float sx, sy;
    gather_node(csr_src, gs, beg, end, node, lane, sx, sy);
    float dv = dinv[node];
    float2 bv = ((const float2*)bias)[lane];
    float2 r;
    r.x = fmaxf(sx * dv + bv.x, 0.0f);
    r.y = fmaxf(sy * dv + bv.y, 0.0f);
    outb[(size_t)node * 64 + lane] = __float22bfloat162_rn(r);
}

// ---- mean pool stage 1 (bf16 input) ----
__global__ __launch_bounds__(256) void pool_kernel(const __hip_bfloat16* __restrict__ a,
                                                   float* __restrict__ pooled, int n) {
    int tid = blockIdx.x * 256 + threadIdx.x;  // 256 blocks -> 65536 threads
    int f = tid & 127;
    int i0 = tid >> 7;  // 0..511
    float s = 0.0f;
    for (int i = i0; i < n; i += 512) s += __bfloat162float(a[(size_t)i * FEAT + f]);
    atomicAdd(&pooled[f], s);
}

// ---- final: out[c] = (pooled/N) . Wc[:,c] + bc[c] ----
__global__ __launch_bounds__(128) void final_kernel(const float* __restrict__ pooled,
                                                    const float* __restrict__ Wc,
                                                    const float* __restrict__ bc,
                                                    float* __restrict__ out,
                                                    int n, int C) {
    __shared__ float p[FEAT];
    int t = threadIdx.x;
    p[t] = pooled[t] * (1.0f / (float)n);
    __syncthreads();
    if (t < C) {
        float acc = bc[t];
        for (int h = 0; h < FEAT; h++)
            acc += p[h] * Wc[h * C + t];
        out[t] = acc;
    }
}

extern "C" void kernel_launch(void* const* d_in, const int* in_sizes, int n_in,
                              void* d_out, int out_size, void* d_ws, size_t ws_size,
                              hipStream_t stream) {
    const float* x  = (const float*)d_in[0];
    const int*   ei = (const int*)d_in[1];
    const float* W1 = (const float*)d_in[2];
    const float* b1 = (const float*)d_in[3];
    const float* W2 = (const float*)d_in[4];
    const float* b2 = (const float*)d_in[5];
    const float* Wc = (const float*)d_in[6];
    const float* bc = (const float*)d_in[7];

    const int N = in_sizes[0] / FEAT;        // 100000
    const int E = in_sizes[1] / 2;           // 1600000
    const int C = out_size;                  // 32
    const int* srcI = ei;
    const int* dstI = ei + E;
    const int NC = (E + CHUNK - 1) / CHUNK;  // edge chunks (98)
    const int NBK = (N + 255) >> 8;          // node buckets (391, <= MAXBUCK)

    // workspace carve (256B aligned)
    auto align256 = [](size_t v) { return (v + 255) & ~(size_t)255; };
    char* w = (char*)d_ws;
    int*            cnt     = (int*)w;            w += align256((size_t)N * 4);
    float*          dinv    = (float*)w;          w += align256((size_t)N * 4);
    int*            cursor  = (int*)w;            w += align256((size_t)N * 4);
    int*            csr_src = (int*)w;            w += align256((size_t)E * 4);
    int*            binned  = (int*)w;            w += align256((size_t)E * 4);
    int*            hist    = (int*)w;            w += align256((size_t)NBK * NC * 4);
    int*            hoff    = (int*)w;            w += align256((size_t)NBK * NC * 4);
    int*            bboff   = (int*)w;            w += align256((size_t)(NBK + 1) * 4);
    unsigned short* Wbf1    = (unsigned short*)w; w += align256((size_t)FEAT * FEAT * 2);
    unsigned short* Wbf2    = (unsigned short*)w; w += align256((size_t)FEAT * FEAT * 2);
    unsigned char*  gbuf    = (unsigned char*)w;  w += align256((size_t)N * FEAT);
    unsigned short* bufA    = (unsigned short*)w; w += align256((size_t)N * FEAT * 2);
    float*          pooled  = (float*)w;          w += align256((size_t)FEAT * 4);

    hipMemsetAsync(pooled, 0, (size_t)FEAT * 4, stream);

    // W pre-pack (both layers, one launch)
    wprep2<<<128, 256, 0, stream>>>(W1, W2, Wbf1, Wbf2);

    // ---- atomic-free CSR build ----
    hist2<<<NC, 256, 0, stream>>>(dstI, hist, E, NC, NBK);
    bucket_offsets<<<1, 512, 0, stream>>>(hist, hoff, bboff, NC, NBK);
    fill2<<<NC, 256, 0, stream>>>(srcI, dstI, hoff, binned, E, NC, NBK);
    bucket_scat<<<NBK, 256, 0, stream>>>(binned, bboff, cnt, dinv, cursor, csr_src, N);

    const int gGemm = (N + 63) / 64;
    const int gAgg = (N + 3) / 4;

    // ---- layer 1 ----
    gemm_mfma<true><<<gGemm, 256, 0, stream>>>(x, Wbf1, dinv, gbuf, N);
    agg_csr<<<gAgg, 256, 0, stream>>>(cursor, cnt, csr_src,
                                      (const unsigned short*)gbuf, dinv, b1,
                                      (__hip_bfloat162*)bufA, N);

    // ---- layer 2 ----
    gemm_mfma<false><<<gGemm, 256, 0, stream>>>(bufA, Wbf2, dinv, gbuf, N);
    agg_csr<<<gAgg, 256, 0, stream>>>(cursor, cnt, csr_src,
                                      (const unsigned short*)gbuf, dinv, b2,
                                      (__hip_bfloat162*)bufA, N);

    // ---- pool + classifier ----
    pool_kernel<<<256, 256, 0, stream>>>((const __hip_bfloat16*)bufA, pooled, N);
    final_kernel<<<1, 128, 0, stream>>>(pooled, Wc, bc, (float*)d_out, N, C);
}

// Round 12
// 368.772 us; speedup vs baseline: 1.4248x; 1.2243x over previous
//
#include <hip/hip_runtime.h>
#include <hip/hip_bf16.h>

// GCN: h1 = relu(Agg(x@W1)+b1); h2 = relu(Agg(h1@W2)+b2); out = mean(h2)@Wc + bc
// Agg via CSR gather; g = (X@W)*dinv stored OCP fp8 e4m3 (128B rows).
// agg_csr is at its structural floor: FETCH = 8 XCDs x 12.8MB gbuf (LLC->L2
// duplication), ~1.8 TB/s effective. 1 node/wave + 100k-wave oversubscription
// is required (r10 A/B: 16-serial-node fusion halved throughput).
// CSR build atomic-free; ALL build kernels >= 391 blocks (r11: 98-block and
// single-block kernels were width-starved, ~270us invisible tail).
// GEMMs: mfma_f32_16x16x32_bf16, LDS-free, W pre-packed to k-block layout.

#define FEAT 128
#define CHUNK 4096      // edges per chunk (391 chunks)
#define MAXBUCK 512     // max node-buckets (N <= 131072); also NC cap
#define ECAP 12288      // LDS edge staging cap in bucket_scat (48 KB of int)

typedef __attribute__((ext_vector_type(8))) short short8;
typedef __attribute__((ext_vector_type(4))) float float4v;
typedef __attribute__((ext_vector_type(2))) float floatx2;

union I4S8 { int4 i; short8 s; };

static __device__ inline unsigned short f2bf(float f) {
    union { __hip_bfloat16 h; unsigned short u; } cv;
    cv.h = __float2bfloat16(f);
    return cv.u;
}

// ---- OCP fp8 e4m3 helpers ----
static __device__ inline floatx2 fp8x2_dec(unsigned int u) {
#if __has_builtin(__builtin_amdgcn_cvt_pk_f32_fp8)
    return __builtin_amdgcn_cvt_pk_f32_fp8((int)u, false);
#else
    floatx2 r;
    unsigned int b0 = u & 0xFFu, b1 = (u >> 8) & 0xFFu;
    r.x = __uint_as_float(((b0 & 0x80u) << 24) | ((b0 & 0x7Fu) << 20)) * 0x1p+120f;
    r.y = __uint_as_float(((b1 & 0x80u) << 24) | ((b1 & 0x7Fu) << 20)) * 0x1p+120f;
    return r;
#endif
}

static __device__ inline unsigned char fp8enc(float f) {
#if __has_builtin(__builtin_amdgcn_cvt_pk_fp8_f32)
    return (unsigned char)(__builtin_amdgcn_cvt_pk_fp8_f32(f, 0.0f, 0, false) & 0xFF);
#else
    unsigned int u = __float_as_uint(f);
    unsigned int s = (u >> 24) & 0x80u;
    float a = fabsf(f);
    a = fminf(a, 448.0f);
    unsigned int code;
    if (a < 0.015625f) {
        code = (unsigned int)(int)rintf(a * 512.0f);
    } else {
        unsigned int au = __float_as_uint(a);
        unsigned int r = au + 0x0007FFFFu + ((au >> 20) & 1u);
        unsigned int e = (r >> 23) - 120u;
        unsigned int m = (r >> 20) & 7u;
        code = (e << 3) | m;
        if (code > 0x7Eu) code = 0x7Eu;
    }
    return (unsigned char)(code | s);
#endif
}

// ---- build phase 1: per-chunk histogram over node buckets (dst>>8) ----
__global__ __launch_bounds__(256) void hist2(const int* __restrict__ dst,
                                             int* __restrict__ hist,
                                             int nE, int NC, int nbuck) {
    __shared__ int h[MAXBUCK];
    int c = blockIdx.x, t = threadIdx.x;
    for (int i = t; i < nbuck; i += 256) h[i] = 0;
    __syncthreads();
    int beg = c * CHUNK, end = min(nE, beg + CHUNK);
    for (int e = beg + t; e < end; e += 256)
        atomicAdd(&h[dst[e] >> 8], 1);
    __syncthreads();
    for (int i = t; i < nbuck; i += 256) hist[i * NC + c] = h[i];
}

// ---- phase 2a: per-bucket totals (wide: one block per bucket) ----
__global__ __launch_bounds__(256) void rowsum_k(const int* __restrict__ hist,
                                                int* __restrict__ btot, int NC) {
    __shared__ int red[256];
    int b = blockIdx.x, t = threadIdx.x;
    int s = 0;
    for (int c = t; c < NC; c += 256) s += hist[b * NC + c];
    red[t] = s;
    __syncthreads();
    for (int o = 128; o > 0; o >>= 1) {
        if (t < o) red[t] += red[t + o];
        __syncthreads();
    }
    if (t == 0) btot[b] = red[0];
}

// ---- phase 2b: exclusive scan of bucket totals (nbuck <= 512) ----
__global__ __launch_bounds__(512) void bscan_k(const int* __restrict__ btot,
                                               int* __restrict__ bboff, int nbuck) {
    __shared__ int sc[512];
    int t = threadIdx.x;
    int v = (t < nbuck) ? btot[t] : 0;
    sc[t] = v;
    __syncthreads();
    for (int o = 1; o < 512; o <<= 1) {
        int add = (t >= o) ? sc[t - o] : 0;
        __syncthreads();
        sc[t] += add;
        __syncthreads();
    }
    if (t < nbuck) {
        bboff[t] = sc[t] - v;
        if (t == nbuck - 1) bboff[nbuck] = sc[t];
    }
}

// ---- phase 2c: per-(bucket,chunk) offsets (wide: block-parallel scan, NC<=512) ----
__global__ __launch_bounds__(512) void rowoff_k(const int* __restrict__ hist,
                                                const int* __restrict__ bboff,
                                                int* __restrict__ hoff, int NC) {
    __shared__ int sc[512];
    int b = blockIdx.x, t = threadIdx.x;
    int v = (t < NC) ? hist[b * NC + t] : 0;
    sc[t] = v;
    __syncthreads();
    for (int o = 1; o < 512; o <<= 1) {
        int add = (t >= o) ? sc[t - o] : 0;
        __syncthreads();
        sc[t] += add;
        __syncthreads();
    }
    if (t < NC) hoff[b * NC + t] = bboff[b] + sc[t] - v;
}

// ---- phase 3: pack (src<<8|dloc) bucket-grouped; LDS cursors ----
__global__ __launch_bounds__(256) void fill2(const int* __restrict__ src,
                                             const int* __restrict__ dst,
                                             const int* __restrict__ off,
                                             int* __restrict__ binned,
                                             int nE, int NC, int nbuck) {
    __shared__ int cur[MAXBUCK];
    int c = blockIdx.x, t = threadIdx.x;
    for (int i = t; i < nbuck; i += 256) cur[i] = off[i * NC + c];
    __syncthreads();
    int beg = c * CHUNK, end = min(nE, beg + CHUNK);
    for (int e = beg + t; e < end; e += 256) {
        int d = dst[e];
        int pos = atomicAdd(&cur[d >> 8], 1);
        binned[pos] = (src[e] << 8) | (d & 255);
    }
}

// ---- phase 4: per-bucket count + dinv + cursor + csr scatter (all LDS) ----
__global__ __launch_bounds__(256) void bucket_scat(const int* __restrict__ binned,
                                                   const int* __restrict__ bboff,
                                                   int* __restrict__ cnt,
                                                   float* __restrict__ dinv,
                                                   int* __restrict__ cursor,
                                                   int* __restrict__ csr_src, int n) {
    __shared__ int se[ECAP];
    __shared__ int lcnt[256];
    __shared__ int lcur[256];
    __shared__ int ssc[256];
    int b = blockIdx.x, t = threadIdx.x;
    int node0 = b << 8;
    int nloc = min(256, n - node0);
    int ebeg = bboff[b], eend = bboff[b + 1];
    int ne = eend - ebeg;
    lcnt[t] = 0;
    __syncthreads();
    bool staged = (ne <= ECAP);
    if (staged) {
        for (int i = t; i < ne; i += 256) {
            int e = binned[ebeg + i];
            se[i] = e;
            atomicAdd(&lcnt[e & 255], 1);
        }
    } else {
        for (int i = t; i < ne; i += 256)
            atomicAdd(&lcnt[binned[ebeg + i] & 255], 1);
    }
    __syncthreads();
    int myc = (t < nloc) ? lcnt[t] : 0;
    ssc[t] = myc;
    __syncthreads();
    for (int o = 1; o < 256; o <<= 1) {
        int add = (t >= o) ? ssc[t - o] : 0;
        __syncthreads();
        ssc[t] += add;
        __syncthreads();
    }
    int excl = ssc[t] - myc;
    if (t < nloc) {
        cnt[node0 + t] = myc;
        dinv[node0 + t] = rsqrtf((float)(myc + 1));
        cursor[node0 + t] = ebeg + excl;   // cursor = start of node's list
        lcur[t] = excl;
    }
    __syncthreads();
    if (staged) {
        for (int i = t; i < ne; i += 256) {
            int e = se[i];
            int pos = atomicAdd(&lcur[e & 255], 1);
            csr_src[ebeg + pos] = ((unsigned int)e) >> 8;
        }
    } else {
        for (int i = t; i < ne; i += 256) {
            int e = binned[ebeg + i];
            int pos = atomicAdd(&lcur[e & 255], 1);
            csr_src[ebeg + pos] = ((unsigned int)e) >> 8;
        }
    }
}

// ---- W pre-pack (both layers) + pooled zero-init ----
__global__ __launch_bounds__(256) void wprep2(const float* __restrict__ W1,
                                              const float* __restrict__ W2,
                                              unsigned short* __restrict__ Wbf1,
                                              unsigned short* __restrict__ Wbf2,
                                              float* __restrict__ pooled) {
    int tid = blockIdx.x * 256 + threadIdx.x;   // 32768 threads
    if (tid < FEAT) pooled[tid] = 0.0f;
    const float* W = (tid < 16384) ? W1 : W2;
    unsigned short* O = (tid < 16384) ? Wbf1 : Wbf2;
    int id = tid & 16383;
    int chunk = id >> 3, j = id & 7;
    int kb = chunk >> 7, nn = chunk & 127;
    O[id] = f2bf(W[(kb * 8 + j) * FEAT + nn]);
}

// ---- MFMA GEMM: gout[N][128](fp8) = bf16(X) @ Wbf * dinv[row] ----
template <bool AFP32>
__global__ __launch_bounds__(256) void gemm_mfma(const void* __restrict__ Xv,
                                                 const unsigned short* __restrict__ Wbf,
                                                 const float* __restrict__ dinv,
                                                 unsigned char* __restrict__ gout,
                                                 int n) {
    int wave = threadIdx.x >> 6, lane = threadIdx.x & 63;
    int m0 = blockIdx.x * 64 + wave * 16;
    if (m0 >= n) return;
    int col = lane & 15, quad = lane >> 4;
    int mc = min(m0 + col, n - 1);

    short8 afr[4];
    if (AFP32) {
        const float* X = (const float*)Xv;
        const float* xr = X + (size_t)mc * FEAT + quad * 8;
#pragma unroll
        for (int ks = 0; ks < 4; ks++) {
            float4 lo = *(const float4*)(xr + ks * 32);
            float4 hi = *(const float4*)(xr + ks * 32 + 4);
            short8 a;
            a[0] = (short)f2bf(lo.x); a[1] = (short)f2bf(lo.y);
            a[2] = (short)f2bf(lo.z); a[3] = (short)f2bf(lo.w);
            a[4] = (short)f2bf(hi.x); a[5] = (short)f2bf(hi.y);
            a[6] = (short)f2bf(hi.z); a[7] = (short)f2bf(hi.w);
            afr[ks] = a;
        }
    } else {
        const int4* X = (const int4*)Xv;
        const int4* xr = X + (size_t)mc * (FEAT / 8) + quad;
#pragma unroll
        for (int ks = 0; ks < 4; ks++) {
            I4S8 u; u.i = xr[ks * 4];
            afr[ks] = u.s;
        }
    }

    float dvr[4];
#pragma unroll
    for (int r = 0; r < 4; r++)
        dvr[r] = dinv[min(m0 + quad * 4 + r, n - 1)];

    const int4* Wb = (const int4*)Wbf;
#pragma unroll
    for (int nt = 0; nt < 8; nt++) {
        float4v acc = {0.f, 0.f, 0.f, 0.f};
#pragma unroll
        for (int ks = 0; ks < 4; ks++) {
            int kb = ks * 4 + quad;
            I4S8 u; u.i = Wb[kb * FEAT + nt * 16 + col];
            acc = __builtin_amdgcn_mfma_f32_16x16x32_bf16(afr[ks], u.s, acc, 0, 0, 0);
        }
#pragma unroll
        for (int r = 0; r < 4; r++) {
            int row = m0 + quad * 4 + r;
            if (row < n)
                gout[(size_t)row * FEAT + nt * 16 + col] = fp8enc(acc[r] * dvr[r]);
        }
    }
}

// ---- gather-sum core for one node (fp8 rows, 2 feats/lane) ----
static __device__ inline void gather_node(const int* __restrict__ csr_src,
                                          const unsigned short* __restrict__ gs,
                                          int beg, int end, int node, int lane,
                                          float& sx, float& sy) {
    floatx2 sl = fp8x2_dec(gs[(size_t)node * 64 + lane]);   // self-loop term
    float ax[4] = {sl.x, 0.f, 0.f, 0.f};
    float ay[4] = {sl.y, 0.f, 0.f, 0.f};
    int j = beg;
    for (; j + 15 < end; j += 16) {
        int sIdx[16];
#pragma unroll
        for (int k = 0; k < 16; k++) sIdx[k] = csr_src[j + k];
        unsigned int uu[16];
#pragma unroll
        for (int k = 0; k < 16; k++) uu[k] = gs[(size_t)sIdx[k] * 64 + lane];
#pragma unroll
        for (int k = 0; k < 16; k++) {
            floatx2 v = fp8x2_dec(uu[k]);
            ax[k & 3] += v.x;
            ay[k & 3] += v.y;
        }
    }
    for (; j + 3 < end; j += 4) {
        int sIdx[4];
#pragma unroll
        for (int k = 0; k < 4; k++) sIdx[k] = csr_src[j + k];
        unsigned int uu[4];
#pragma unroll
        for (int k = 0; k < 4; k++) uu[k] = gs[(size_t)sIdx[k] * 64 + lane];
#pragma unroll
        for (int k = 0; k < 4; k++) {
            floatx2 v = fp8x2_dec(uu[k]);
            ax[k] += v.x;
            ay[k] += v.y;
        }
    }
    for (; j < end; j++) {
        floatx2 v = fp8x2_dec(gs[(size_t)csr_src[j] * 64 + lane]);
        ax[0] += v.x;
        ay[0] += v.y;
    }
    sx = (ax[0] + ax[1]) + (ax[2] + ax[3]);
    sy = (ay[0] + ay[1]) + (ay[2] + ay[3]);
}

// ---- agg: CSR gather + bias + relu -> bf16 rows (1 node per wave) ----
__global__ __launch_bounds__(256) void agg_csr(const int* __restrict__ cursor,
                                               const int* __restrict__ cnt,
                                               const int* __restrict__ csr_src,
                                               const unsigned short* __restrict__ gs,
                                               const float* __restrict__ dinv,
                                               const float* __restrict__ bias,
                                               __hip_bfloat162* __restrict__ outb,
                                               int n) {
    int node = blockIdx.x * 4 + (threadIdx.x >> 6);
    if (node >= n) return;
    int lane = threadIdx.x & 63;
    int beg = cursor[node];
    int end = beg + cnt[node];
    float sx, sy;
    gather_node(csr_src, gs, beg, end, node, lane, sx, sy);
    float dv = dinv[node];
    float2 bv = ((const float2*)bias)[lane];
    float2 r;
    r.x = fmaxf(sx * dv + bv.x, 0.0f);
    r.y = fmaxf(sy * dv + bv.y, 0.0f);
    outb[(size_t)node * 64 + lane] = __float22bfloat162_rn(r);
}

// ---- mean pool stage 1 (bf16 input, 1024 blocks) ----
__global__ __launch_bounds__(256) void pool_kernel(const __hip_bfloat16* __restrict__ a,
                                                   float* __restrict__ pooled, int n) {
    int tid = blockIdx.x * 256 + threadIdx.x;  // 1024 blocks -> 262144 threads
    int f = tid & 127;
    int i0 = tid >> 7;  // 0..2047
    float s = 0.0f;
    for (int i = i0; i < n; i += 2048) s += __bfloat162float(a[(size_t)i * FEAT + f]);
    atomicAdd(&pooled[f], s);
}

// ---- final: out[c] = (pooled/N) . Wc[:,c] + bc[c] ----
__global__ __launch_bounds__(128) void final_kernel(const float* __restrict__ pooled,
                                                    const float* __restrict__ Wc,
                                                    const float* __restrict__ bc,
                                                    float* __restrict__ out,
                                                    int n, int C) {
    __shared__ float p[FEAT];
    int t = threadIdx.x;
    p[t] = pooled[t] * (1.0f / (float)n);
    __syncthreads();
    if (t < C) {
        float acc = bc[t];
        for (int h = 0; h < FEAT; h++)
            acc += p[h] * Wc[h * C + t];
        out[t] = acc;
    }
}

extern "C" void kernel_launch(void* const* d_in, const int* in_sizes, int n_in,
                              void* d_out, int out_size, void* d_ws, size_t ws_size,
                              hipStream_t stream) {
    const float* x  = (const float*)d_in[0];
    const int*   ei = (const int*)d_in[1];
    const float* W1 = (const float*)d_in[2];
    const float* b1 = (const float*)d_in[3];
    const float* W2 = (const float*)d_in[4];
    const float* b2 = (const float*)d_in[5];
    const float* Wc = (const float*)d_in[6];
    const float* bc = (const float*)d_in[7];

    const int N = in_sizes[0] / FEAT;        // 100000
    const int E = in_sizes[1] / 2;           // 1600000
    const int C = out_size;                  // 32
    const int* srcI = ei;
    const int* dstI = ei + E;
    const int NC = (E + CHUNK - 1) / CHUNK;  // edge chunks (391, <= 512)
    const int NBK = (N + 255) >> 8;          // node buckets (391, <= MAXBUCK)

    // workspace carve (256B aligned)
    auto align256 = [](size_t v) { return (v + 255) & ~(size_t)255; };
    char* w = (char*)d_ws;
    int*            cnt     = (int*)w;            w += align256((size_t)N * 4);
    float*          dinv    = (float*)w;          w += align256((size_t)N * 4);
    int*            cursor  = (int*)w;            w += align256((size_t)N * 4);
    int*            csr_src = (int*)w;            w += align256((size_t)E * 4);
    int*            binned  = (int*)w;            w += align256((size_t)E * 4);
    int*            hist    = (int*)w;            w += align256((size_t)NBK * NC * 4);
    int*            hoff    = (int*)w;            w += align256((size_t)NBK * NC * 4);
    int*            btot    = (int*)w;            w += align256((size_t)NBK * 4);
    int*            bboff   = (int*)w;            w += align256((size_t)(NBK + 1) * 4);
    unsigned short* Wbf1    = (unsigned short*)w; w += align256((size_t)FEAT * FEAT * 2);
    unsigned short* Wbf2    = (unsigned short*)w; w += align256((size_t)FEAT * FEAT * 2);
    unsigned char*  gbuf    = (unsigned char*)w;  w += align256((size_t)N * FEAT);
    unsigned short* bufA    = (unsigned short*)w; w += align256((size_t)N * FEAT * 2);
    float*          pooled  = (float*)w;          w += align256((size_t)FEAT * 4);

    // W pre-pack (both layers) + pooled zero
    wprep2<<<128, 256, 0, stream>>>(W1, W2, Wbf1, Wbf2, pooled);

    // ---- atomic-free CSR build (all kernels >= 391 blocks except bscan) ----
    hist2<<<NC, 256, 0, stream>>>(dstI, hist, E, NC, NBK);
    rowsum_k<<<NBK, 256, 0, stream>>>(hist, btot, NC);
    bscan_k<<<1, 512, 0, stream>>>(btot, bboff, NBK);
    rowoff_k<<<NBK, 512, 0, stream>>>(hist, bboff, hoff, NC);
    fill2<<<NC, 256, 0, stream>>>(srcI, dstI, hoff, binned, E, NC, NBK);
    bucket_scat<<<NBK, 256, 0, stream>>>(binned, bboff, cnt, dinv, cursor, csr_src, N);

    const int gGemm = (N + 63) / 64;
    const int gAgg = (N + 3) / 4;

    // ---- layer 1 ----
    gemm_mfma<true><<<gGemm, 256, 0, stream>>>(x, Wbf1, dinv, gbuf, N);
    agg_csr<<<gAgg, 256, 0, stream>>>(cursor, cnt, csr_src,
                                      (const unsigned short*)gbuf, dinv, b1,
                                      (__hip_bfloat162*)bufA, N);

    // ---- layer 2 ----
    gemm_mfma<false><<<gGemm, 256, 0, stream>>>(bufA, Wbf2, dinv, gbuf, N);
    agg_csr<<<gAgg, 256, 0, stream>>>(cursor, cnt, csr_src,
                                      (const unsigned short*)gbuf, dinv, b2,
                                      (__hip_bfloat162*)bufA, N);

    // ---- pool + classifier ----
    pool_kernel<<<1024, 256, 0, stream>>>((const __hip_bfloat16*)bufA, pooled, N);
    final_kernel<<<1, 128, 0, stream>>>(pooled, Wc, bc, (float*)d_out, N, C);
}